// Round 1
// 125.816 us; speedup vs baseline: 1.0231x; 1.0231x over previous
//
#include <hip/hip_runtime.h>
#include <math.h>

// Problem constants (match reference setup_inputs)
#define BN     2
#define QN     4096
#define LN     1024
#define TOPKN  128
#define PI_F   3.14159265358979323846f

// log2 of the per-step omega ratio: omegas = 10 * 2^(i*LOG2R)
// LOG2R0 = log2(12.8)/7, LOG2R1 = log2(3.2)/7
#define LOG2R0 0.52543879f
#define LOG2R1 0.23972456f

// union-window capacity (keys) and padded pitch for score/P buffers
// pitch 332 f32 (1328 B): P-row ds_read_b128 lanes spread over 8 banks (2-way, free)
#define NCMAX  320
#define PFP    332

typedef __attribute__((ext_vector_type(8))) short  s16x8;
typedef __attribute__((ext_vector_type(4))) short  s16x4;
typedef __attribute__((ext_vector_type(4))) float  f32x4;
typedef unsigned short u16;

__device__ __forceinline__ u16 f2bf(float f) {
    unsigned int u = __float_as_uint(f);
    u = (u + 0x7FFFu + ((u >> 16) & 1u)) >> 16;   // RNE
    return (u16)u;
}

// Tiled B-operand layouts: one wave MFMA-fragment load = contiguous memory.
// Weights wT: [n/16][k/32][n%16][k%32]  (wave load spans 1024B contiguous)
__device__ __forceinline__ size_t wtile(int n, int k, int K) {
    return (size_t)((n >> 4) * (K >> 5) + (k >> 5)) * 512 + (n & 15) * 32 + (k & 31);
}
// K cache: [b][l/16][d/8][l%16][d%8]  (256B contiguous per quad)
__device__ __forceinline__ size_t kidx(int b, int l, int d) {
    return (((size_t)(b * 64 + (l >> 4)) * 16 + (d >> 3)) * 16 + (l & 15)) * 8 + (d & 7);
}
// V cache: [b][n/16][k/8][n%16][k%8]  (256B contiguous per quad)
__device__ __forceinline__ size_t vidx(int b, int n, int k) {
    return (((size_t)(b * 8 + (n >> 4)) * 128 + (k >> 3)) * 16 + (n & 15)) * 8 + (k & 7);
}

// ---------------------------------------------------------------------------
// Launch 1: prep, 225 blocks x 1024 threads (single occupancy round at any
// VGPR count). kv: 64 blocks; q: 128; transpose: 32 (8 tiles each); sort: 1.
// ---------------------------------------------------------------------------
struct KvS { u16 tok[32 * 264]; u16 stage[256 * 40]; float vtile[128][40]; };
struct QS  { float shx[128]; u16 gam[32 * 72]; u16 xq[32 * 264]; u16 stage[256 * 40]; };
struct TrS { float tile[8][32][33]; };
struct SoS { int hist[1024]; int cur[1024]; };
union PrepS { KvS kv; QS q; TrS tr; SoS so; };

__global__ __launch_bounds__(1024) void prep_kernel(
    const float* __restrict__ tokens, const float* __restrict__ kv_W,
    const float* __restrict__ x, const float* __restrict__ query_W,
    const float* __restrict__ query_b, const float* __restrict__ q_W,
    const float* __restrict__ outW, const float* __restrict__ bandW,
    const float* __restrict__ modW, const float* __restrict__ hvW,
    const int* __restrict__ gDp, const int* __restrict__ gHp,
    const int* __restrict__ gWp, const int* __restrict__ gTp,
    u16* __restrict__ qall, u16* __restrict__ kbf, u16* __restrict__ vtbf,
    u16* __restrict__ outT, u16* __restrict__ bandT,
    u16* __restrict__ modT, u16* __restrict__ hvT,
    int* __restrict__ perm, int* __restrict__ ssort)
{
    __shared__ __align__(16) PrepS sm;
    const int bid = blockIdx.x;
    const int t   = threadIdx.x;
    const int wid = t >> 6, lane = t & 63;
    const int quad = lane >> 4, l16 = lane & 15;

    if (bid < 64) {
        // ---- kv path: 32 token rows/block, 16 waves ----
        int l0 = bid * 32;
        int b = l0 >> 10, lloc = l0 & 1023;
        #pragma unroll
        for (int i = 0; i < 8; i++) {
            int idx = i * 1024 + t; int row = idx >> 8, col = idx & 255;
            sm.kv.tok[row * 264 + col] = f2bf(tokens[(size_t)(l0 + row) * 256 + col]);
        }
        int m0 = (wid & 1) * 16;
        int c0 = (wid >> 1) * 32;
        f32x4 acc[2];
        acc[0] = (f32x4){0.f, 0.f, 0.f, 0.f};
        acc[1] = (f32x4){0.f, 0.f, 0.f, 0.f};
        for (int kc = 0; kc < 8; kc++) {
            __syncthreads();
            #pragma unroll
            for (int i = 0; i < 8; i++) {
                int idx = i * 1024 + t; int k = idx >> 8, n = idx & 255;
                sm.kv.stage[n * 40 + k] = f2bf(kv_W[(size_t)(kc * 32 + k) * 256 + n]);
            }
            __syncthreads();
            s16x8 a = *(const s16x8*)&sm.kv.tok[(m0 + l16) * 264 + kc * 32 + quad * 8];
            #pragma unroll
            for (int sub = 0; sub < 2; sub++) {
                s16x8 bfr = *(const s16x8*)&sm.kv.stage[(c0 + sub * 16 + l16) * 40 + quad * 8];
                acc[sub] = __builtin_amdgcn_mfma_f32_16x16x32_bf16(a, bfr, acc[sub], 0, 0, 0);
            }
        }
        #pragma unroll
        for (int sub = 0; sub < 2; sub++) {
            int col = c0 + sub * 16 + l16;
            if (col < 128) {
                #pragma unroll
                for (int r = 0; r < 4; r++) {
                    int lg = l0 + m0 + quad * 4 + r;
                    kbf[kidx(lg >> 10, lg & 1023, col)] = f2bf(acc[sub][r]);
                }
            } else {
                #pragma unroll
                for (int r = 0; r < 4; r++)
                    sm.kv.vtile[col - 128][m0 + quad * 4 + r] = acc[sub][r];
            }
        }
        __syncthreads();
        {   // vtbf (tiled): 4 bf16 per thread, 8B store within one k-chunk
            int col = t >> 3, rg = (t & 7) * 4;
            float4 v4 = *(const float4*)&sm.kv.vtile[col][rg];
            s16x4 pk;
            pk[0] = (short)f2bf(v4.x); pk[1] = (short)f2bf(v4.y);
            pk[2] = (short)f2bf(v4.z); pk[3] = (short)f2bf(v4.w);
            *(s16x4*)&vtbf[vidx(b, col, lloc + rg)] = pk;
        }
    } else if (bid < 192) {
        // ---- q path: 32 queries/block, 16 waves ----
        int p0 = (bid - 64) * 32;
        if (t < 128) sm.q.shx[t] = x[p0 * 4 + t];
        __syncthreads();
        #pragma unroll
        for (int j = 0; j < 2; j++) {
            int e = t * 2 + j;
            int g = e >> 6, f = e & 63;
            int c = f >> 4, jj = f & 15, oi = jj & 7;
            float om = 10.0f * exp2f((float)oi * LOG2R0);
            float arg = PI_F * sm.q.shx[g * 4 + c] * om;
            sm.q.gam[g * 72 + f] = f2bf((jj < 8) ? __sinf(arg) : __cosf(arg));
        }
        int m0 = (wid & 1) * 16;
        {   // stage 1: xq = relu(gamma @ query_W + b)
            int c0 = (wid >> 1) * 32;
            f32x4 acc[2];
            acc[0] = (f32x4){0.f, 0.f, 0.f, 0.f};
            acc[1] = (f32x4){0.f, 0.f, 0.f, 0.f};
            for (int kc = 0; kc < 2; kc++) {
                __syncthreads();
                #pragma unroll
                for (int i = 0; i < 8; i++) {
                    int idx = i * 1024 + t; int k = idx >> 8, n = idx & 255;
                    sm.q.stage[n * 40 + k] = f2bf(query_W[(size_t)(kc * 32 + k) * 256 + n]);
                }
                __syncthreads();
                s16x8 a = *(const s16x8*)&sm.q.gam[(m0 + l16) * 72 + kc * 32 + quad * 8];
                #pragma unroll
                for (int sub = 0; sub < 2; sub++) {
                    s16x8 bfr = *(const s16x8*)&sm.q.stage[(c0 + sub * 16 + l16) * 40 + quad * 8];
                    acc[sub] = __builtin_amdgcn_mfma_f32_16x16x32_bf16(a, bfr, acc[sub], 0, 0, 0);
                }
            }
            #pragma unroll
            for (int sub = 0; sub < 2; sub++) {
                int col = c0 + sub * 16 + l16;
                float bias = query_b[col];
                #pragma unroll
                for (int r = 0; r < 4; r++)
                    sm.q.xq[(m0 + quad * 4 + r) * 264 + col] = f2bf(fmaxf(acc[sub][r] + bias, 0.f));
            }
        }
        {   // stage 2: q = xq @ q_W  (stored bf16 — bit-identical to old fused-side f2bf)
            int n0q = (wid >> 1) * 16;
            f32x4 acc2 = (f32x4){0.f, 0.f, 0.f, 0.f};
            for (int kc = 0; kc < 8; kc++) {
                __syncthreads();
                #pragma unroll
                for (int i = 0; i < 4; i++) {
                    int idx = i * 1024 + t; int k = idx >> 7, n = idx & 127;
                    sm.q.stage[n * 40 + k] = f2bf(q_W[(size_t)(kc * 32 + k) * 128 + n]);
                }
                __syncthreads();
                s16x8 a = *(const s16x8*)&sm.q.xq[(m0 + l16) * 264 + kc * 32 + quad * 8];
                s16x8 bfr = *(const s16x8*)&sm.q.stage[(n0q + l16) * 40 + quad * 8];
                acc2 = __builtin_amdgcn_mfma_f32_16x16x32_bf16(a, bfr, acc2, 0, 0, 0);
            }
            #pragma unroll
            for (int r = 0; r < 4; r++)
                qall[(size_t)(p0 + m0 + quad * 4 + r) * 128 + n0q + l16] = f2bf(acc2[r]);
        }
    } else if (bid < 224) {
        // ---- transpose path: 8 32x32 tiles/block, all staged at once ----
        int base = (bid - 192) * 8;
        int tx = t & 31, ty = (t >> 5) & 31;
        #pragma unroll
        for (int it = 0; it < 8; it++) {
            int lt_g = base + it;
            const float* src; int K, lt;
            if (lt_g < 32)       { src = outW;  K = 128; lt = lt_g; }
            else if (lt_g < 64)  { src = bandW; K = 128; lt = lt_g - 32; }
            else if (lt_g < 192) { src = modW;  K = 512; lt = lt_g - 64; }
            else                 { src = hvW;   K = 256; lt = lt_g - 192; }
            int tk = K >> 5;
            int k0 = (lt % tk) * 32, n0 = (lt / tk) * 32;
            sm.tr.tile[it][ty][tx] = src[(size_t)(k0 + ty) * 256 + n0 + tx];
        }
        __syncthreads();
        #pragma unroll
        for (int it = 0; it < 8; it++) {
            int lt_g = base + it;
            u16* dst; int K, lt;
            if (lt_g < 32)       { dst = outT;  K = 128; lt = lt_g; }
            else if (lt_g < 64)  { dst = bandT; K = 128; lt = lt_g - 32; }
            else if (lt_g < 192) { dst = modT;  K = 512; lt = lt_g - 64; }
            else                 { dst = hvT;   K = 256; lt = lt_g - 192; }
            int tk = K >> 5;
            int k0 = (lt % tk) * 32, n0 = (lt / tk) * 32;
            dst[wtile(n0 + ty, k0 + tx, K)] = f2bf(sm.tr.tile[it][tx][ty]);
        }
    } else {
        // ---- sort path: counting sort by window start; wave-shuffle scan ----
        int gD = gDp[0], gH = gHp[0], gW = gWp[0], gT = gTp[0];
        int Ng = gD * gH * gW * gT;
        sm.so.hist[t] = 0;
        __syncthreads();
        int sarr[4];
        #pragma unroll
        for (int i = 0; i < 4; i++) {
            int q = i * 1024 + t;
            float4 xv = *(const float4*)&x[q * 4];
            int zi = (int)(xv.x * (float)gD);
            int yi = (int)(xv.y * (float)gH);
            int xi = (int)(xv.z * (float)gW);
            int ti = (int)(xv.w * (float)gT);
            int idx = ((ti * gD + zi) * gH + yi) * gW + xi;
            float tt = (float)idx / (float)Ng;
            int s = (int)ceilf(tt * (float)LN - ((float)(TOPKN / 2) + 0.5f));
            s = min(max(s, 0), LN - TOPKN);
            sarr[i] = s;
            atomicAdd(&sm.so.hist[s], 1);
        }
        __syncthreads();
        int cnt = sm.so.hist[t];
        int incl = cnt;
        #pragma unroll
        for (int off = 1; off < 64; off <<= 1) {
            int u = __shfl_up(incl, off);
            if (lane >= off) incl += u;
        }
        if (lane == 63) sm.so.cur[wid] = incl;
        __syncthreads();
        if (wid == 0) {
            int v = (lane < 16) ? sm.so.cur[lane] : 0;
            #pragma unroll
            for (int off = 1; off < 16; off <<= 1) {
                int u = __shfl_up(v, off);
                if (lane >= off) v += u;
            }
            if (lane < 16) sm.so.cur[lane] = v;
        }
        __syncthreads();
        int woff = wid ? sm.so.cur[wid - 1] : 0;
        sm.so.hist[t] = woff + incl - cnt;   // exclusive offset → placement cursor
        __syncthreads();
        #pragma unroll
        for (int i = 0; i < 4; i++) {
            int q = i * 1024 + t;
            int pos = atomicAdd(&sm.so.hist[sarr[i]], 1);
            perm[pos] = q;
            ssort[pos] = sarr[i];
        }
    }
}

// ---------------------------------------------------------------------------
// Launch 2: fused. 512 blocks x 1024 threads, 2 blocks/CU. 16 SORTED queries.
// Gamma via native v_exp/v_sin; softmax via __expf; q staged as bf16.
// ---------------------------------------------------------------------------
__global__ __launch_bounds__(1024, 8) void fused_kernel(
    const float* __restrict__ x,
    const u16* __restrict__ kbf, const u16* __restrict__ vtbf,
    const u16* __restrict__ qall,
    const int* __restrict__ perm, const int* __restrict__ ssort,
    const u16* __restrict__ outT, const float* __restrict__ out_b,
    const u16* __restrict__ bandT, const float* __restrict__ band_b,
    const u16* __restrict__ modT, const float* __restrict__ mod_b,
    const u16* __restrict__ hvT, const float* __restrict__ hv_b,
    const float* __restrict__ outl_W, const float* __restrict__ outl_b,
    float* __restrict__ out)
{
    const int bid = blockIdx.x;
    const int b   = bid >> 8;
    const int sp0 = (bid & 255) * 16;
    const int t   = threadIdx.x;
    const int wid = t >> 6, lane = t & 63;
    const int quad = lane >> 4, l16 = lane & 15;

    __shared__ __align__(16) u16 q_bf[16 * 136];
    __shared__ __align__(16) u16 gam_lds[32 * 72];
    __shared__ __align__(16) float scores32[32 * PFP];   // scores / P_bf / modu+s01
    __shared__ __align__(16) u16 o_lds[16 * 136];
    __shared__ float fin[256];
    __shared__ float sh_xc[64];
    __shared__ int sh_pq[16], sh_s[16];

    u16* modu_lds = (u16*)scores32;
    u16* s01_lds  = ((u16*)scores32) + 16 * 264;

    if (t < 16) { sh_pq[t] = perm[sp0 + t]; sh_s[t] = ssort[sp0 + t]; }
    __syncthreads();                                             // b1

    {   // stage q (bf16 A-rows, already bf16 in global)
        int m = t >> 6, d = (t & 63) * 2;
        *(unsigned int*)&q_bf[m * 136 + d] =
            *(const unsigned int*)&qall[(size_t)sh_pq[m] * 128 + d];
    }
    if (t < 64) sh_xc[t] = x[(size_t)sh_pq[t >> 2] * 4 + (t & 3)];
    __syncthreads();                                             // b2

    // layer gammas (sorted order) — consumed after b6, any barrier covers
    #pragma unroll
    for (int j = 0; j < 2; j++) {
        int e = t * 2 + j;
        int l = e >> 10, g = (e >> 6) & 15, f = e & 63;
        int c = f >> 4, jj = f & 15, oi = jj & 7;
        float om = 10.0f * exp2f((float)oi * (l ? LOG2R1 : LOG2R0));
        float arg = PI_F * sh_xc[g * 4 + c] * om;
        gam_lds[(l * 16 + g) * 72 + f] = f2bf((jj < 8) ? __sinf(arg) : __cosf(arg));
    }

    const int u0    = sh_s[0] & ~15;           // 16-aligned for K tiling
    const int ncols = min((sh_s[15] + 128 - u0 + 31) & ~31, NCMAX);
    const int nsub  = ncols >> 4;
    const int nkc   = ncols >> 5;

    // ---- scores, both heads in one pass: job = (head, subtile) ----
    {
        s16x8 aq00 = *(const s16x8*)&q_bf[l16 * 136 + quad * 8];
        s16x8 aq01 = *(const s16x8*)&q_bf[l16 * 136 + 32 + quad * 8];
        s16x8 aq10 = *(const s16x8*)&q_bf[l16 * 136 + 64 + quad * 8];
        s16x8 aq11 = *(const s16x8*)&q_bf[l16 * 136 + 96 + quad * 8];
        for (int j = wid; j < 2 * nsub; j += 16) {
            int h = (j >= nsub) ? 1 : 0;
            int sub = j - h * nsub;
            int lrow = u0 + sub * 16 + l16;
            f32x4 acc = (f32x4){0.f, 0.f, 0.f, 0.f};
            s16x8 b0 = *(const s16x8*)&kbf[kidx(b, lrow, h * 64 + quad * 8)];
            s16x8 b1 = *(const s16x8*)&kbf[kidx(b, lrow, h * 64 + 32 + quad * 8)];
            acc = __builtin_amdgcn_mfma_f32_16x16x32_bf16(h ? aq10 : aq00, b0, acc, 0, 0, 0);
            acc = __builtin_amdgcn_mfma_f32_16x16x32_bf16(h ? aq11 : aq01, b1, acc, 0, 0, 0);
            #pragma unroll
            for (int r = 0; r < 4; r++)
                scores32[(h * 16 + quad * 4 + r) * PFP + sub * 16 + l16] = acc[r];
        }
    }
    __syncthreads();                                             // b3

    // ---- masked softmax, both rows per wave; bf16 P written in-place ----
    {
        int g = wid;
        int sg = sh_s[g];
        #pragma unroll
        for (int rr = 0; rr < 2; rr++) {
            int row = g + rr * 16;
            float vals[5]; int ok[5];
            float mx = -1e30f;
            #pragma unroll
            for (int i = 0; i < 5; i++) {
                int c = lane + 64 * i;
                float v = scores32[row * PFP + c] * 0.125f;
                int key = u0 + c;
                int o2 = (c < ncols) && (key >= sg) && (key < sg + 128);
                vals[i] = v; ok[i] = o2;
                if (o2) mx = fmaxf(mx, v);
            }
            #pragma unroll
            for (int off = 1; off < 64; off <<= 1) mx = fmaxf(mx, __shfl_xor(mx, off));
            float sum = 0.f, e5[5];
            #pragma unroll
            for (int i = 0; i < 5; i++) {
                float e = ok[i] ? __expf(vals[i] - mx) : 0.f;
                e5[i] = e; sum += e;
            }
            #pragma unroll
            for (int off = 1; off < 64; off <<= 1) sum += __shfl_xor(sum, off);
            float inv = 1.f / sum;
            u16* prow = (u16*)&scores32[row * PFP];   // in-place bf16 P (row-local)
            #pragma unroll
            for (int i = 0; i < 5; i++) {
                int c = lane + 64 * i;
                if (c < ncols) prow[c] = f2bf(e5[i] * inv);
            }
        }
    }
    __syncthreads();                                             // b4

    // ---- P @ V (MFMA): one wave per 16-col tile, full k-range ----
    if (wid < 8) {
        int n0 = wid * 16;
        int hh = n0 >> 6;
        const u16* prow = (const u16*)&scores32[(hh * 16 + l16) * PFP];
        f32x4 acc = (f32x4){0.f, 0.f, 0.f, 0.f};
        for (int kc = 0; kc < nkc; kc++) {
            s16x8 a = *(const s16x8*)&prow[kc * 32 + quad * 8];
            int koff = u0 + kc * 32 + quad * 8;
            koff = min(koff, 1016);   // clamp pure-garbage chunks (P=0 there)
            s16x8 bfr = *(const s16x8*)&vtbf[vidx(b, n0 + l16, koff)];
            acc = __builtin_amdgcn_mfma_f32_16x16x32_bf16(a, bfr, acc, 0, 0, 0);
        }
        #pragma unroll
        for (int r = 0; r < 4; r++)
            o_lds[(quad * 4 + r) * 136 + n0 + l16] = f2bf(acc[r]);
    }
    __syncthreads();                                             // b5

    // ---------------- MFMA MLP: 16 waves x 16 cols, tiled weights ----------------
    const int n0 = wid * 16;
    float m0f[4];

    {   // modulation = o @ out_W + out_b (K=128)
        f32x4 acc = (f32x4){0.f, 0.f, 0.f, 0.f};
        #pragma unroll
        for (int kc = 0; kc < 4; kc++) {
            s16x8 a = *(const s16x8*)&o_lds[l16 * 136 + kc * 32 + quad * 8];
            s16x8 bfr = *(const s16x8*)&outT[wtile(n0 + l16, kc * 32 + quad * 8, 128)];
            acc = __builtin_amdgcn_mfma_f32_16x16x32_bf16(a, bfr, acc, 0, 0, 0);
        }
        int col = n0 + l16;
        float bias = out_b[col];
        #pragma unroll
        for (int r = 0; r < 4; r++)
            modu_lds[(quad * 4 + r) * 264 + col] = f2bf(acc[r] + bias);
    }
    __syncthreads();                                             // b6

    #pragma unroll
    for (int l = 0; l < 2; l++) {
        f32x4 acc1 = (f32x4){0.f, 0.f, 0.f, 0.f};
        f32x4 acc2 = (f32x4){0.f, 0.f, 0.f, 0.f};
        #pragma unroll
        for (int kc = 0; kc < 2; kc++) {
            s16x8 a = *(const s16x8*)&gam_lds[(l * 16 + l16) * 72 + kc * 32 + quad * 8];
            s16x8 bfr = *(const s16x8*)&bandT[wtile(n0 + l16, l * 64 + kc * 32 + quad * 8, 128)];
            acc1 = __builtin_amdgcn_mfma_f32_16x16x32_bf16(a, bfr, acc1, 0, 0, 0);
        }
        #pragma unroll
        for (int kc = 0; kc < 8; kc++) {
            s16x8 a = *(const s16x8*)&modu_lds[l16 * 264 + kc * 32 + quad * 8];
            s16x8 bfr = *(const s16x8*)&modT[wtile(n0 + l16, l * 256 + kc * 32 + quad * 8, 512)];
            acc2 = __builtin_amdgcn_mfma_f32_16x16x32_bf16(a, bfr, acc2, 0, 0, 0);
        }
        int col = n0 + l16;
        float bb = band_b[l * 256 + col];
        float mb = mod_b[l * 256 + col];
        #pragma unroll
        for (int r = 0; r < 4; r++) {
            float hval = fmaxf(acc1[r] + bb, 0.f);
            float mval = fmaxf(hval + acc2[r] + mb, 0.f);
            if (l == 0) m0f[r] = mval;
            else s01_lds[(quad * 4 + r) * 264 + col] = f2bf(m0f[r] + mval);
        }
    }
    __syncthreads();                                             // b7

    {   // h_v1 = relu(s01 @ hv_W + hv_b) + scalar head
        f32x4 acc = (f32x4){0.f, 0.f, 0.f, 0.f};
        #pragma unroll
        for (int kc = 0; kc < 8; kc++) {
            s16x8 a = *(const s16x8*)&s01_lds[l16 * 264 + kc * 32 + quad * 8];
            s16x8 bfr = *(const s16x8*)&hvT[wtile(n0 + l16, kc * 32 + quad * 8, 256)];
            acc = __builtin_amdgcn_mfma_f32_16x16x32_bf16(a, bfr, acc, 0, 0, 0);
        }
        int col = n0 + l16;
        float w0 = outl_W[col], w1 = outl_W[256 + col], hb = hv_b[col];
        #pragma unroll
        for (int r = 0; r < 4; r++) {
            float hvv = fmaxf(acc[r] + hb, 0.f);
            float pv = m0f[r] * w0 + hvv * w1;
            #pragma unroll
            for (int off = 1; off < 16; off <<= 1) pv += __shfl_xor(pv, off);
            if (l16 == 0) fin[wid * 16 + quad * 4 + r] = pv;
        }
    }
    __syncthreads();                                             // b8
    if (t < 16) {
        float s2 = outl_b[0] + outl_b[1];
        #pragma unroll
        for (int w = 0; w < 16; w++) s2 += fin[w * 16 + t];
        out[(size_t)b * QN + sh_pq[t]] = s2;   // scatter by permutation
    }
}

// ---------------------------------------------------------------------------
extern "C" void kernel_launch(void* const* d_in, const int* in_sizes, int n_in,
                              void* d_out, int out_size, void* d_ws, size_t ws_size,
                              hipStream_t stream)
{
    const float* x       = (const float*)d_in[0];
    const float* tokens  = (const float*)d_in[1];
    const float* query_W = (const float*)d_in[2];
    const float* query_b = (const float*)d_in[3];
    const float* q_W     = (const float*)d_in[4];
    const float* kv_W    = (const float*)d_in[5];
    const float* out_W   = (const float*)d_in[6];
    const float* out_b   = (const float*)d_in[7];
    const float* band_W  = (const float*)d_in[8];
    const float* band_b  = (const float*)d_in[9];
    const float* mod_W   = (const float*)d_in[10];
    const float* mod_b   = (const float*)d_in[11];
    const float* hv_W    = (const float*)d_in[12];
    const float* hv_b    = (const float*)d_in[13];
    const float* outl_W  = (const float*)d_in[14];
    const float* outl_b  = (const float*)d_in[15];
    const int*   gD      = (const int*)d_in[16];
    const int*   gH      = (const int*)d_in[17];
    const int*   gW      = (const int*)d_in[18];
    const int*   gT      = (const int*)d_in[19];

    float* ws   = (float*)d_ws;
    u16* qall   = (u16*)ws;                         // 4096*128 bf16 (region keeps old 2MB slot)
    u16* wb = (u16*)(ws + 524288);
    u16* kbf   = wb;                                // 2*1024*128 bf16 (tiled)
    u16* vtbf  = wb + 262144;                       // 2*128*1024 bf16 (tiled)
    u16* outT  = wb + 524288;                       // 32768 (tiled)
    u16* bandT = wb + 557056;                       // 32768 (tiled)
    u16* modT  = wb + 589824;                       // 131072 (tiled)
    u16* hvT   = wb + 720896;                       // 65536 (tiled)
    int* perm  = (int*)(wb + 786432);               // 4096 ints
    int* ssort = perm + 4096;                       // 4096 ints
    float* out = (float*)d_out;

    prep_kernel<<<225, 1024, 0, stream>>>(tokens, kv_W, x, query_W, query_b, q_W,
                                          out_W, band_W, mod_W, hv_W,
                                          gD, gH, gW, gT,
                                          qall, kbf, vtbf, outT, bandT, modT, hvT,
                                          perm, ssort);
    fused_kernel<<<512, 1024, 0, stream>>>(x, kbf, vtbf, qall, perm, ssort,
        outT, out_b, bandT, band_b, modT, mod_b, hvT, hv_b,
        outl_W, outl_b, out);
}

// Round 2
// 124.980 us; speedup vs baseline: 1.0299x; 1.0067x over previous
//
#include <hip/hip_runtime.h>
#include <math.h>

// Problem constants (match reference setup_inputs)
#define BN     2
#define QN     4096
#define LN     1024
#define TOPKN  128
#define PI_F   3.14159265358979323846f

// log2 of the per-step omega ratio: omegas = 10 * 2^(i*LOG2R)
// LOG2R0 = log2(12.8)/7, LOG2R1 = log2(3.2)/7
#define LOG2R0 0.52543879f
#define LOG2R1 0.23972456f

// union-window capacity (keys) and padded pitch for score/P buffers
// pitch 332 f32 (1328 B): P-row ds_read_b128 lanes spread over 8 banks (2-way, free)
#define NCMAX  320
#define PFP    332

typedef __attribute__((ext_vector_type(8))) short  s16x8;
typedef __attribute__((ext_vector_type(4))) short  s16x4;
typedef __attribute__((ext_vector_type(4))) float  f32x4;
typedef unsigned short u16;

__device__ __forceinline__ u16 f2bf(float f) {
    unsigned int u = __float_as_uint(f);
    u = (u + 0x7FFFu + ((u >> 16) & 1u)) >> 16;   // RNE
    return (u16)u;
}

// Build a 16x16x32 B-fragment directly from fp32 row-major global memory.
// lane's 8 k-values are strided by the row pitch; conversion is the same RNE
// f2bf as the old LDS-staging path (bit-identical results).
__device__ __forceinline__ s16x8 ldB(const float* __restrict__ base, int stride) {
    s16x8 r;
    #pragma unroll
    for (int jj = 0; jj < 8; jj++) r[jj] = (short)f2bf(base[(size_t)jj * stride]);
    return r;
}

// Tiled B-operand layouts: one wave MFMA-fragment load = contiguous memory.
// Weights wT: [n/16][k/32][n%16][k%32]  (wave load spans 1024B contiguous)
__device__ __forceinline__ size_t wtile(int n, int k, int K) {
    return (size_t)((n >> 4) * (K >> 5) + (k >> 5)) * 512 + (n & 15) * 32 + (k & 31);
}
// K cache: [b][l/16][d/8][l%16][d%8]  (256B contiguous per quad)
__device__ __forceinline__ size_t kidx(int b, int l, int d) {
    return (((size_t)(b * 64 + (l >> 4)) * 16 + (d >> 3)) * 16 + (l & 15)) * 8 + (d & 7);
}
// V cache: [b][n/16][k/8][n%16][k%8]  (256B contiguous per quad)
__device__ __forceinline__ size_t vidx(int b, int n, int k) {
    return (((size_t)(b * 8 + (n >> 4)) * 128 + (k >> 3)) * 16 + (n & 15)) * 8 + (k & 7);
}

// ---------------------------------------------------------------------------
// Launch 1: prep, 225 blocks x 1024 threads.
// kv: 64 blocks (1 barrier); q: 128 (3 barriers); transpose: 32; sort: 1.
// Weight B-fragments are loaded directly from fp32 global (no LDS staging,
// no per-kc barriers).
// ---------------------------------------------------------------------------
struct KvS { u16 tok[32 * 264]; };
struct QS  { float shx[128]; u16 gam[32 * 72]; u16 xq[32 * 264]; };
struct TrS { float tile[8][32][33]; };
struct SoS { int hist[1024]; int cur[1024]; };
union PrepS { KvS kv; QS q; TrS tr; SoS so; };

__global__ __launch_bounds__(1024) void prep_kernel(
    const float* __restrict__ tokens, const float* __restrict__ kv_W,
    const float* __restrict__ x, const float* __restrict__ query_W,
    const float* __restrict__ query_b, const float* __restrict__ q_W,
    const float* __restrict__ outW, const float* __restrict__ bandW,
    const float* __restrict__ modW, const float* __restrict__ hvW,
    const int* __restrict__ gDp, const int* __restrict__ gHp,
    const int* __restrict__ gWp, const int* __restrict__ gTp,
    u16* __restrict__ qall, u16* __restrict__ kbf, u16* __restrict__ vtbf,
    u16* __restrict__ outT, u16* __restrict__ bandT,
    u16* __restrict__ modT, u16* __restrict__ hvT,
    int* __restrict__ perm, int* __restrict__ ssort)
{
    __shared__ __align__(16) PrepS sm;
    const int bid = blockIdx.x;
    const int t   = threadIdx.x;
    const int wid = t >> 6, lane = t & 63;
    const int quad = lane >> 4, l16 = lane & 15;

    if (bid < 64) {
        // ---- kv path: 32 token rows/block, 16 waves, single barrier ----
        int l0 = bid * 32;
        int b = l0 >> 10, lloc = l0 & 1023;
        #pragma unroll
        for (int i = 0; i < 8; i++) {
            int idx = i * 1024 + t; int row = idx >> 8, col = idx & 255;
            sm.kv.tok[row * 264 + col] = f2bf(tokens[(size_t)(l0 + row) * 256 + col]);
        }
        __syncthreads();
        int m0 = (wid & 1) * 16;
        int c0 = (wid >> 1) * 32;
        f32x4 acc[2];
        acc[0] = (f32x4){0.f, 0.f, 0.f, 0.f};
        acc[1] = (f32x4){0.f, 0.f, 0.f, 0.f};
        for (int kc = 0; kc < 8; kc++) {
            s16x8 a = *(const s16x8*)&sm.kv.tok[(m0 + l16) * 264 + kc * 32 + quad * 8];
            #pragma unroll
            for (int sub = 0; sub < 2; sub++) {
                s16x8 bfr = ldB(&kv_W[(size_t)(kc * 32 + quad * 8) * 256 + c0 + sub * 16 + l16], 256);
                acc[sub] = __builtin_amdgcn_mfma_f32_16x16x32_bf16(a, bfr, acc[sub], 0, 0, 0);
            }
        }
        #pragma unroll
        for (int sub = 0; sub < 2; sub++) {
            int col = c0 + sub * 16 + l16;
            if (col < 128) {
                #pragma unroll
                for (int r = 0; r < 4; r++)
                    kbf[kidx(b, lloc + m0 + quad * 4 + r, col)] = f2bf(acc[sub][r]);
            } else {
                s16x4 pk;
                pk[0] = (short)f2bf(acc[sub][0]); pk[1] = (short)f2bf(acc[sub][1]);
                pk[2] = (short)f2bf(acc[sub][2]); pk[3] = (short)f2bf(acc[sub][3]);
                *(s16x4*)&vtbf[vidx(b, col - 128, lloc + m0 + quad * 4)] = pk;
            }
        }
    } else if (bid < 192) {
        // ---- q path: 32 queries/block, 16 waves, 3 barriers ----
        int p0 = (bid - 64) * 32;
        if (t < 128) sm.q.shx[t] = x[p0 * 4 + t];
        __syncthreads();
        #pragma unroll
        for (int j = 0; j < 2; j++) {
            int e = t * 2 + j;
            int g = e >> 6, f = e & 63;
            int c = f >> 4, jj = f & 15, oi = jj & 7;
            float om = 10.0f * exp2f((float)oi * LOG2R0);
            float arg = PI_F * sm.q.shx[g * 4 + c] * om;
            sm.q.gam[g * 72 + f] = f2bf((jj < 8) ? __sinf(arg) : __cosf(arg));
        }
        __syncthreads();
        int m0 = (wid & 1) * 16;
        {   // stage 1: xq = relu(gamma @ query_W + b), B direct from global
            int c0 = (wid >> 1) * 32;
            f32x4 acc[2];
            acc[0] = (f32x4){0.f, 0.f, 0.f, 0.f};
            acc[1] = (f32x4){0.f, 0.f, 0.f, 0.f};
            for (int kc = 0; kc < 2; kc++) {
                s16x8 a = *(const s16x8*)&sm.q.gam[(m0 + l16) * 72 + kc * 32 + quad * 8];
                #pragma unroll
                for (int sub = 0; sub < 2; sub++) {
                    s16x8 bfr = ldB(&query_W[(size_t)(kc * 32 + quad * 8) * 256 + c0 + sub * 16 + l16], 256);
                    acc[sub] = __builtin_amdgcn_mfma_f32_16x16x32_bf16(a, bfr, acc[sub], 0, 0, 0);
                }
            }
            #pragma unroll
            for (int sub = 0; sub < 2; sub++) {
                int col = c0 + sub * 16 + l16;
                float bias = query_b[col];
                #pragma unroll
                for (int r = 0; r < 4; r++)
                    sm.q.xq[(m0 + quad * 4 + r) * 264 + col] = f2bf(fmaxf(acc[sub][r] + bias, 0.f));
            }
        }
        __syncthreads();
        {   // stage 2: q = xq @ q_W (bf16 out), B direct from global
            int n0q = (wid >> 1) * 16;
            f32x4 acc2 = (f32x4){0.f, 0.f, 0.f, 0.f};
            for (int kc = 0; kc < 8; kc++) {
                s16x8 a = *(const s16x8*)&sm.q.xq[(m0 + l16) * 264 + kc * 32 + quad * 8];
                s16x8 bfr = ldB(&q_W[(size_t)(kc * 32 + quad * 8) * 128 + n0q + l16], 128);
                acc2 = __builtin_amdgcn_mfma_f32_16x16x32_bf16(a, bfr, acc2, 0, 0, 0);
            }
            #pragma unroll
            for (int r = 0; r < 4; r++)
                qall[(size_t)(p0 + m0 + quad * 4 + r) * 128 + n0q + l16] = f2bf(acc2[r]);
        }
    } else if (bid < 224) {
        // ---- transpose path: 8 32x32 tiles/block, all staged at once ----
        int base = (bid - 192) * 8;
        int tx = t & 31, ty = (t >> 5) & 31;
        #pragma unroll
        for (int it = 0; it < 8; it++) {
            int lt_g = base + it;
            const float* src; int K, lt;
            if (lt_g < 32)       { src = outW;  K = 128; lt = lt_g; }
            else if (lt_g < 64)  { src = bandW; K = 128; lt = lt_g - 32; }
            else if (lt_g < 192) { src = modW;  K = 512; lt = lt_g - 64; }
            else                 { src = hvW;   K = 256; lt = lt_g - 192; }
            int tk = K >> 5;
            int k0 = (lt % tk) * 32, n0 = (lt / tk) * 32;
            sm.tr.tile[it][ty][tx] = src[(size_t)(k0 + ty) * 256 + n0 + tx];
        }
        __syncthreads();
        #pragma unroll
        for (int it = 0; it < 8; it++) {
            int lt_g = base + it;
            u16* dst; int K, lt;
            if (lt_g < 32)       { dst = outT;  K = 128; lt = lt_g; }
            else if (lt_g < 64)  { dst = bandT; K = 128; lt = lt_g - 32; }
            else if (lt_g < 192) { dst = modT;  K = 512; lt = lt_g - 64; }
            else                 { dst = hvT;   K = 256; lt = lt_g - 192; }
            int tk = K >> 5;
            int k0 = (lt % tk) * 32, n0 = (lt / tk) * 32;
            dst[wtile(n0 + ty, k0 + tx, K)] = f2bf(sm.tr.tile[it][tx][ty]);
        }
    } else {
        // ---- sort path: counting sort by window start; wave-shuffle scan ----
        int gD = gDp[0], gH = gHp[0], gW = gWp[0], gT = gTp[0];
        int Ng = gD * gH * gW * gT;
        sm.so.hist[t] = 0;
        __syncthreads();
        int sarr[4];
        #pragma unroll
        for (int i = 0; i < 4; i++) {
            int q = i * 1024 + t;
            float4 xv = *(const float4*)&x[q * 4];
            int zi = (int)(xv.x * (float)gD);
            int yi = (int)(xv.y * (float)gH);
            int xi = (int)(xv.z * (float)gW);
            int ti = (int)(xv.w * (float)gT);
            int idx = ((ti * gD + zi) * gH + yi) * gW + xi;
            float tt = (float)idx / (float)Ng;
            int s = (int)ceilf(tt * (float)LN - ((float)(TOPKN / 2) + 0.5f));
            s = min(max(s, 0), LN - TOPKN);
            sarr[i] = s;
            atomicAdd(&sm.so.hist[s], 1);
        }
        __syncthreads();
        int cnt = sm.so.hist[t];
        int incl = cnt;
        #pragma unroll
        for (int off = 1; off < 64; off <<= 1) {
            int u = __shfl_up(incl, off);
            if (lane >= off) incl += u;
        }
        if (lane == 63) sm.so.cur[wid] = incl;
        __syncthreads();
        if (wid == 0) {
            int v = (lane < 16) ? sm.so.cur[lane] : 0;
            #pragma unroll
            for (int off = 1; off < 16; off <<= 1) {
                int u = __shfl_up(v, off);
                if (lane >= off) v += u;
            }
            if (lane < 16) sm.so.cur[lane] = v;
        }
        __syncthreads();
        int woff = wid ? sm.so.cur[wid - 1] : 0;
        sm.so.hist[t] = woff + incl - cnt;   // exclusive offset → placement cursor
        __syncthreads();
        #pragma unroll
        for (int i = 0; i < 4; i++) {
            int q = i * 1024 + t;
            int pos = atomicAdd(&sm.so.hist[sarr[i]], 1);
            perm[pos] = q;
            ssort[pos] = sarr[i];
        }
    }
}

// ---------------------------------------------------------------------------
// Launch 2: fused. 512 blocks x 1024 threads, 2 blocks/CU. 16 SORTED queries.
// PV: P zero-filled to NCMAX → fixed-trip k-loop (unrollable, loads pipeline).
// ---------------------------------------------------------------------------
__global__ __launch_bounds__(1024, 8) void fused_kernel(
    const float* __restrict__ x,
    const u16* __restrict__ kbf, const u16* __restrict__ vtbf,
    const u16* __restrict__ qall,
    const int* __restrict__ perm, const int* __restrict__ ssort,
    const u16* __restrict__ outT, const float* __restrict__ out_b,
    const u16* __restrict__ bandT, const float* __restrict__ band_b,
    const u16* __restrict__ modT, const float* __restrict__ mod_b,
    const u16* __restrict__ hvT, const float* __restrict__ hv_b,
    const float* __restrict__ outl_W, const float* __restrict__ outl_b,
    float* __restrict__ out)
{
    const int bid = blockIdx.x;
    const int b   = bid >> 8;
    const int sp0 = (bid & 255) * 16;
    const int t   = threadIdx.x;
    const int wid = t >> 6, lane = t & 63;
    const int quad = lane >> 4, l16 = lane & 15;

    __shared__ __align__(16) u16 q_bf[16 * 136];
    __shared__ __align__(16) u16 gam_lds[32 * 72];
    __shared__ __align__(16) float scores32[32 * PFP];   // scores / P_bf / modu+s01
    __shared__ __align__(16) u16 o_lds[16 * 136];
    __shared__ float fin[256];
    __shared__ float sh_xc[64];
    __shared__ int sh_pq[16], sh_s[16];

    u16* modu_lds = (u16*)scores32;
    u16* s01_lds  = ((u16*)scores32) + 16 * 264;

    if (t < 16) { sh_pq[t] = perm[sp0 + t]; sh_s[t] = ssort[sp0 + t]; }
    __syncthreads();                                             // b1

    {   // stage q (bf16 A-rows, already bf16 in global)
        int m = t >> 6, d = (t & 63) * 2;
        *(unsigned int*)&q_bf[m * 136 + d] =
            *(const unsigned int*)&qall[(size_t)sh_pq[m] * 128 + d];
    }
    if (t < 64) sh_xc[t] = x[(size_t)sh_pq[t >> 2] * 4 + (t & 3)];
    __syncthreads();                                             // b2

    // layer gammas (sorted order) — consumed after b6, any barrier covers
    #pragma unroll
    for (int j = 0; j < 2; j++) {
        int e = t * 2 + j;
        int l = e >> 10, g = (e >> 6) & 15, f = e & 63;
        int c = f >> 4, jj = f & 15, oi = jj & 7;
        float om = 10.0f * exp2f((float)oi * (l ? LOG2R1 : LOG2R0));
        float arg = PI_F * sh_xc[g * 4 + c] * om;
        gam_lds[(l * 16 + g) * 72 + f] = f2bf((jj < 8) ? __sinf(arg) : __cosf(arg));
    }

    const int u0    = sh_s[0] & ~15;           // 16-aligned for K tiling
    const int ncols = min((sh_s[15] + 128 - u0 + 31) & ~31, NCMAX);
    const int nsub  = ncols >> 4;

    // ---- scores, both heads in one pass: job = (head, subtile) ----
    {
        s16x8 aq00 = *(const s16x8*)&q_bf[l16 * 136 + quad * 8];
        s16x8 aq01 = *(const s16x8*)&q_bf[l16 * 136 + 32 + quad * 8];
        s16x8 aq10 = *(const s16x8*)&q_bf[l16 * 136 + 64 + quad * 8];
        s16x8 aq11 = *(const s16x8*)&q_bf[l16 * 136 + 96 + quad * 8];
        for (int j = wid; j < 2 * nsub; j += 16) {
            int h = (j >= nsub) ? 1 : 0;
            int sub = j - h * nsub;
            int lrow = u0 + sub * 16 + l16;
            f32x4 acc = (f32x4){0.f, 0.f, 0.f, 0.f};
            s16x8 b0 = *(const s16x8*)&kbf[kidx(b, lrow, h * 64 + quad * 8)];
            s16x8 b1 = *(const s16x8*)&kbf[kidx(b, lrow, h * 64 + 32 + quad * 8)];
            acc = __builtin_amdgcn_mfma_f32_16x16x32_bf16(h ? aq10 : aq00, b0, acc, 0, 0, 0);
            acc = __builtin_amdgcn_mfma_f32_16x16x32_bf16(h ? aq11 : aq01, b1, acc, 0, 0, 0);
            #pragma unroll
            for (int r = 0; r < 4; r++)
                scores32[(h * 16 + quad * 4 + r) * PFP + sub * 16 + l16] = acc[r];
        }
    }
    __syncthreads();                                             // b3

    // ---- masked softmax; bf16 P written in-place, zero-filled to NCMAX ----
    {
        int g = wid;
        int sg = sh_s[g];
        #pragma unroll
        for (int rr = 0; rr < 2; rr++) {
            int row = g + rr * 16;
            float vals[5]; int ok[5];
            float mx = -1e30f;
            #pragma unroll
            for (int i = 0; i < 5; i++) {
                int c = lane + 64 * i;
                float v = scores32[row * PFP + c] * 0.125f;
                int key = u0 + c;
                int o2 = (c < ncols) && (key >= sg) && (key < sg + 128);
                vals[i] = v; ok[i] = o2;
                if (o2) mx = fmaxf(mx, v);
            }
            #pragma unroll
            for (int off = 1; off < 64; off <<= 1) mx = fmaxf(mx, __shfl_xor(mx, off));
            float sum = 0.f, e5[5];
            #pragma unroll
            for (int i = 0; i < 5; i++) {
                float e = ok[i] ? __expf(vals[i] - mx) : 0.f;
                e5[i] = e; sum += e;
            }
            #pragma unroll
            for (int off = 1; off < 64; off <<= 1) sum += __shfl_xor(sum, off);
            float inv = 1.f / sum;
            u16* prow = (u16*)&scores32[row * PFP];   // in-place bf16 P (row-local)
            #pragma unroll
            for (int i = 0; i < 5; i++) {
                int c = lane + 64 * i;
                prow[c] = f2bf(e5[i] * inv);          // 0 beyond ncols (ok=0)
            }
        }
    }
    __syncthreads();                                             // b4

    // ---- P @ V (MFMA): one wave per 16-col tile, fixed-trip k-loop ----
    if (wid < 8) {
        int n0 = wid * 16;
        int hh = n0 >> 6;
        const u16* prow = (const u16*)&scores32[(hh * 16 + l16) * PFP];
        f32x4 acc = (f32x4){0.f, 0.f, 0.f, 0.f};
        for (int kc = 0; kc < (NCMAX >> 5); kc++) {
            s16x8 a = *(const s16x8*)&prow[kc * 32 + quad * 8];
            int koff = u0 + kc * 32 + quad * 8;
            koff = min(koff, 1016);   // OOB chunks: P=0 there, V stays valid
            s16x8 bfr = *(const s16x8*)&vtbf[vidx(b, n0 + l16, koff)];
            acc = __builtin_amdgcn_mfma_f32_16x16x32_bf16(a, bfr, acc, 0, 0, 0);
        }
        #pragma unroll
        for (int r = 0; r < 4; r++)
            o_lds[(quad * 4 + r) * 136 + n0 + l16] = f2bf(acc[r]);
    }
    __syncthreads();                                             // b5

    // ---------------- MFMA MLP: 16 waves x 16 cols, tiled weights ----------------
    const int n0 = wid * 16;
    float m0f[4];

    {   // modulation = o @ out_W + out_b (K=128)
        f32x4 acc = (f32x4){0.f, 0.f, 0.f, 0.f};
        #pragma unroll
        for (int kc = 0; kc < 4; kc++) {
            s16x8 a = *(const s16x8*)&o_lds[l16 * 136 + kc * 32 + quad * 8];
            s16x8 bfr = *(const s16x8*)&outT[wtile(n0 + l16, kc * 32 + quad * 8, 128)];
            acc = __builtin_amdgcn_mfma_f32_16x16x32_bf16(a, bfr, acc, 0, 0, 0);
        }
        int col = n0 + l16;
        float bias = out_b[col];
        #pragma unroll
        for (int r = 0; r < 4; r++)
            modu_lds[(quad * 4 + r) * 264 + col] = f2bf(acc[r] + bias);
    }
    __syncthreads();                                             // b6

    #pragma unroll
    for (int l = 0; l < 2; l++) {
        f32x4 acc1 = (f32x4){0.f, 0.f, 0.f, 0.f};
        f32x4 acc2 = (f32x4){0.f, 0.f, 0.f, 0.f};
        #pragma unroll
        for (int kc = 0; kc < 2; kc++) {
            s16x8 a = *(const s16x8*)&gam_lds[(l * 16 + l16) * 72 + kc * 32 + quad * 8];
            s16x8 bfr = *(const s16x8*)&bandT[wtile(n0 + l16, l * 64 + kc * 32 + quad * 8, 128)];
            acc1 = __builtin_amdgcn_mfma_f32_16x16x32_bf16(a, bfr, acc1, 0, 0, 0);
        }
        #pragma unroll
        for (int kc = 0; kc < 8; kc++) {
            s16x8 a = *(const s16x8*)&modu_lds[l16 * 264 + kc * 32 + quad * 8];
            s16x8 bfr = *(const s16x8*)&modT[wtile(n0 + l16, l * 256 + kc * 32 + quad * 8, 512)];
            acc2 = __builtin_amdgcn_mfma_f32_16x16x32_bf16(a, bfr, acc2, 0, 0, 0);
        }
        int col = n0 + l16;
        float bb = band_b[l * 256 + col];
        float mb = mod_b[l * 256 + col];
        #pragma unroll
        for (int r = 0; r < 4; r++) {
            float hval = fmaxf(acc1[r] + bb, 0.f);
            float mval = fmaxf(hval + acc2[r] + mb, 0.f);
            if (l == 0) m0f[r] = mval;
            else s01_lds[(quad * 4 + r) * 264 + col] = f2bf(m0f[r] + mval);
        }
    }
    __syncthreads();                                             // b7

    {   // h_v1 = relu(s01 @ hv_W + hv_b) + scalar head
        f32x4 acc = (f32x4){0.f, 0.f, 0.f, 0.f};
        #pragma unroll
        for (int kc = 0; kc < 8; kc++) {
            s16x8 a = *(const s16x8*)&s01_lds[l16 * 264 + kc * 32 + quad * 8];
            s16x8 bfr = *(const s16x8*)&hvT[wtile(n0 + l16, kc * 32 + quad * 8, 256)];
            acc = __builtin_amdgcn_mfma_f32_16x16x32_bf16(a, bfr, acc, 0, 0, 0);
        }
        int col = n0 + l16;
        float w0 = outl_W[col], w1 = outl_W[256 + col], hb = hv_b[col];
        #pragma unroll
        for (int r = 0; r < 4; r++) {
            float hvv = fmaxf(acc[r] + hb, 0.f);
            float pv = m0f[r] * w0 + hvv * w1;
            #pragma unroll
            for (int off = 1; off < 16; off <<= 1) pv += __shfl_xor(pv, off);
            if (l16 == 0) fin[wid * 16 + quad * 4 + r] = pv;
        }
    }
    __syncthreads();                                             // b8
    if (t < 16) {
        float s2 = outl_b[0] + outl_b[1];
        #pragma unroll
        for (int w = 0; w < 16; w++) s2 += fin[w * 16 + t];
        out[(size_t)b * QN + sh_pq[t]] = s2;   // scatter by permutation
    }
}

// ---------------------------------------------------------------------------
extern "C" void kernel_launch(void* const* d_in, const int* in_sizes, int n_in,
                              void* d_out, int out_size, void* d_ws, size_t ws_size,
                              hipStream_t stream)
{
    const float* x       = (const float*)d_in[0];
    const float* tokens  = (const float*)d_in[1];
    const float* query_W = (const float*)d_in[2];
    const float* query_b = (const float*)d_in[3];
    const float* q_W     = (const float*)d_in[4];
    const float* kv_W    = (const float*)d_in[5];
    const float* out_W   = (const float*)d_in[6];
    const float* out_b   = (const float*)d_in[7];
    const float* band_W  = (const float*)d_in[8];
    const float* band_b  = (const float*)d_in[9];
    const float* mod_W   = (const float*)d_in[10];
    const float* mod_b   = (const float*)d_in[11];
    const float* hv_W    = (const float*)d_in[12];
    const float* hv_b    = (const float*)d_in[13];
    const float* outl_W  = (const float*)d_in[14];
    const float* outl_b  = (const float*)d_in[15];
    const int*   gD      = (const int*)d_in[16];
    const int*   gH      = (const int*)d_in[17];
    const int*   gW      = (const int*)d_in[18];
    const int*   gT      = (const int*)d_in[19];

    float* ws   = (float*)d_ws;
    u16* qall   = (u16*)ws;                         // 4096*128 bf16
    u16* wb = (u16*)(ws + 524288);
    u16* kbf   = wb;                                // 2*1024*128 bf16 (tiled)
    u16* vtbf  = wb + 262144;                       // 2*128*1024 bf16 (tiled)
    u16* outT  = wb + 524288;                       // 32768 (tiled)
    u16* bandT = wb + 557056;                       // 32768 (tiled)
    u16* modT  = wb + 589824;                       // 131072 (tiled)
    u16* hvT   = wb + 720896;                       // 65536 (tiled)
    int* perm  = (int*)(wb + 786432);               // 4096 ints
    int* ssort = perm + 4096;                       // 4096 ints
    float* out = (float*)d_out;

    prep_kernel<<<225, 1024, 0, stream>>>(tokens, kv_W, x, query_W, query_b, q_W,
                                          out_W, band_W, mod_W, hv_W,
                                          gD, gH, gW, gT,
                                          qall, kbf, vtbf, outT, bandT, modT, hvT,
                                          perm, ssort);
    fused_kernel<<<512, 1024, 0, stream>>>(x, kbf, vtbf, qall, perm, ssort,
        outT, out_b, bandT, band_b, modT, mod_b, hvT, hv_b,
        outl_W, outl_b, out);
}

// Round 3
// 121.567 us; speedup vs baseline: 1.0588x; 1.0281x over previous
//
#include <hip/hip_runtime.h>
#include <math.h>

// Problem constants (match reference setup_inputs)
#define BN     2
#define QN     4096
#define LN     1024
#define TOPKN  128
#define PI_F   3.14159265358979323846f

// log2 of the per-step omega ratio: omegas = 10 * 2^(i*LOG2R)
// LOG2R0 = log2(12.8)/7, LOG2R1 = log2(3.2)/7
#define LOG2R0 0.52543879f
#define LOG2R1 0.23972456f

// union-window capacity (keys) for a 32-query sorted group, and padded pitch.
// PFP=388: 388 mod 32 = 4 -> 16 consecutive rows spread over 8 banks (2-way, free)
#define NCMAX  384
#define PFP    388

typedef __attribute__((ext_vector_type(8))) short  s16x8;
typedef __attribute__((ext_vector_type(4))) short  s16x4;
typedef __attribute__((ext_vector_type(4))) float  f32x4;
typedef unsigned short u16;

__device__ __forceinline__ u16 f2bf(float f) {
    unsigned int u = __float_as_uint(f);
    u = (u + 0x7FFFu + ((u >> 16) & 1u)) >> 16;   // RNE
    return (u16)u;
}

// Build a 16x16x32 B-fragment directly from fp32 row-major global memory.
__device__ __forceinline__ s16x8 ldB(const float* __restrict__ base, int stride) {
    s16x8 r;
    #pragma unroll
    for (int jj = 0; jj < 8; jj++) r[jj] = (short)f2bf(base[(size_t)jj * stride]);
    return r;
}

// Tiled B-operand layouts: one wave MFMA-fragment load = contiguous memory.
// Weights wT: [n/16][k/32][n%16][k%32]  (wave load spans 1024B contiguous)
__device__ __forceinline__ size_t wtile(int n, int k, int K) {
    return (size_t)((n >> 4) * (K >> 5) + (k >> 5)) * 512 + (n & 15) * 32 + (k & 31);
}
// K cache: [b][l/16][d/8][l%16][d%8]  (256B contiguous per quad)
__device__ __forceinline__ size_t kidx(int b, int l, int d) {
    return (((size_t)(b * 64 + (l >> 4)) * 16 + (d >> 3)) * 16 + (l & 15)) * 8 + (d & 7);
}
// V cache: [b][n/16][k/8][n%16][k%8]  (256B contiguous per quad)
__device__ __forceinline__ size_t vidx(int b, int n, int k) {
    return (((size_t)(b * 8 + (n >> 4)) * 128 + (k >> 3)) * 16 + (n & 15)) * 8 + (k & 7);
}

// ---------------------------------------------------------------------------
// Launch 1: prep, 225 blocks x 1024 threads (unchanged from round 2).
// ---------------------------------------------------------------------------
struct KvS { u16 tok[32 * 264]; };
struct QS  { float shx[128]; u16 gam[32 * 72]; u16 xq[32 * 264]; };
struct TrS { float tile[8][32][33]; };
struct SoS { int hist[1024]; int cur[1024]; };
union PrepS { KvS kv; QS q; TrS tr; SoS so; };

__global__ __launch_bounds__(1024) void prep_kernel(
    const float* __restrict__ tokens, const float* __restrict__ kv_W,
    const float* __restrict__ x, const float* __restrict__ query_W,
    const float* __restrict__ query_b, const float* __restrict__ q_W,
    const float* __restrict__ outW, const float* __restrict__ bandW,
    const float* __restrict__ modW, const float* __restrict__ hvW,
    const int* __restrict__ gDp, const int* __restrict__ gHp,
    const int* __restrict__ gWp, const int* __restrict__ gTp,
    u16* __restrict__ qall, u16* __restrict__ kbf, u16* __restrict__ vtbf,
    u16* __restrict__ outT, u16* __restrict__ bandT,
    u16* __restrict__ modT, u16* __restrict__ hvT,
    int* __restrict__ perm, int* __restrict__ ssort)
{
    __shared__ __align__(16) PrepS sm;
    const int bid = blockIdx.x;
    const int t   = threadIdx.x;
    const int wid = t >> 6, lane = t & 63;
    const int quad = lane >> 4, l16 = lane & 15;

    if (bid < 64) {
        // ---- kv path: 32 token rows/block, 16 waves, single barrier ----
        int l0 = bid * 32;
        int b = l0 >> 10, lloc = l0 & 1023;
        #pragma unroll
        for (int i = 0; i < 8; i++) {
            int idx = i * 1024 + t; int row = idx >> 8, col = idx & 255;
            sm.kv.tok[row * 264 + col] = f2bf(tokens[(size_t)(l0 + row) * 256 + col]);
        }
        __syncthreads();
        int m0 = (wid & 1) * 16;
        int c0 = (wid >> 1) * 32;
        f32x4 acc[2];
        acc[0] = (f32x4){0.f, 0.f, 0.f, 0.f};
        acc[1] = (f32x4){0.f, 0.f, 0.f, 0.f};
        for (int kc = 0; kc < 8; kc++) {
            s16x8 a = *(const s16x8*)&sm.kv.tok[(m0 + l16) * 264 + kc * 32 + quad * 8];
            #pragma unroll
            for (int sub = 0; sub < 2; sub++) {
                s16x8 bfr = ldB(&kv_W[(size_t)(kc * 32 + quad * 8) * 256 + c0 + sub * 16 + l16], 256);
                acc[sub] = __builtin_amdgcn_mfma_f32_16x16x32_bf16(a, bfr, acc[sub], 0, 0, 0);
            }
        }
        #pragma unroll
        for (int sub = 0; sub < 2; sub++) {
            int col = c0 + sub * 16 + l16;
            if (col < 128) {
                #pragma unroll
                for (int r = 0; r < 4; r++)
                    kbf[kidx(b, lloc + m0 + quad * 4 + r, col)] = f2bf(acc[sub][r]);
            } else {
                s16x4 pk;
                pk[0] = (short)f2bf(acc[sub][0]); pk[1] = (short)f2bf(acc[sub][1]);
                pk[2] = (short)f2bf(acc[sub][2]); pk[3] = (short)f2bf(acc[sub][3]);
                *(s16x4*)&vtbf[vidx(b, col - 128, lloc + m0 + quad * 4)] = pk;
            }
        }
    } else if (bid < 192) {
        // ---- q path: 32 queries/block, 16 waves, 3 barriers ----
        int p0 = (bid - 64) * 32;
        if (t < 128) sm.q.shx[t] = x[p0 * 4 + t];
        __syncthreads();
        #pragma unroll
        for (int j = 0; j < 2; j++) {
            int e = t * 2 + j;
            int g = e >> 6, f = e & 63;
            int c = f >> 4, jj = f & 15, oi = jj & 7;
            float om = 10.0f * exp2f((float)oi * LOG2R0);
            float arg = PI_F * sm.q.shx[g * 4 + c] * om;
            sm.q.gam[g * 72 + f] = f2bf((jj < 8) ? __sinf(arg) : __cosf(arg));
        }
        __syncthreads();
        int m0 = (wid & 1) * 16;
        {   // stage 1: xq = relu(gamma @ query_W + b), B direct from global
            int c0 = (wid >> 1) * 32;
            f32x4 acc[2];
            acc[0] = (f32x4){0.f, 0.f, 0.f, 0.f};
            acc[1] = (f32x4){0.f, 0.f, 0.f, 0.f};
            for (int kc = 0; kc < 2; kc++) {
                s16x8 a = *(const s16x8*)&sm.q.gam[(m0 + l16) * 72 + kc * 32 + quad * 8];
                #pragma unroll
                for (int sub = 0; sub < 2; sub++) {
                    s16x8 bfr = ldB(&query_W[(size_t)(kc * 32 + quad * 8) * 256 + c0 + sub * 16 + l16], 256);
                    acc[sub] = __builtin_amdgcn_mfma_f32_16x16x32_bf16(a, bfr, acc[sub], 0, 0, 0);
                }
            }
            #pragma unroll
            for (int sub = 0; sub < 2; sub++) {
                int col = c0 + sub * 16 + l16;
                float bias = query_b[col];
                #pragma unroll
                for (int r = 0; r < 4; r++)
                    sm.q.xq[(m0 + quad * 4 + r) * 264 + col] = f2bf(fmaxf(acc[sub][r] + bias, 0.f));
            }
        }
        __syncthreads();
        {   // stage 2: q = xq @ q_W (bf16 out), B direct from global
            int n0q = (wid >> 1) * 16;
            f32x4 acc2 = (f32x4){0.f, 0.f, 0.f, 0.f};
            for (int kc = 0; kc < 8; kc++) {
                s16x8 a = *(const s16x8*)&sm.q.xq[(m0 + l16) * 264 + kc * 32 + quad * 8];
                s16x8 bfr = ldB(&q_W[(size_t)(kc * 32 + quad * 8) * 128 + n0q + l16], 128);
                acc2 = __builtin_amdgcn_mfma_f32_16x16x32_bf16(a, bfr, acc2, 0, 0, 0);
            }
            #pragma unroll
            for (int r = 0; r < 4; r++)
                qall[(size_t)(p0 + m0 + quad * 4 + r) * 128 + n0q + l16] = f2bf(acc2[r]);
        }
    } else if (bid < 224) {
        // ---- transpose path: 8 32x32 tiles/block, all staged at once ----
        int base = (bid - 192) * 8;
        int tx = t & 31, ty = (t >> 5) & 31;
        #pragma unroll
        for (int it = 0; it < 8; it++) {
            int lt_g = base + it;
            const float* src; int K, lt;
            if (lt_g < 32)       { src = outW;  K = 128; lt = lt_g; }
            else if (lt_g < 64)  { src = bandW; K = 128; lt = lt_g - 32; }
            else if (lt_g < 192) { src = modW;  K = 512; lt = lt_g - 64; }
            else                 { src = hvW;   K = 256; lt = lt_g - 192; }
            int tk = K >> 5;
            int k0 = (lt % tk) * 32, n0 = (lt / tk) * 32;
            sm.tr.tile[it][ty][tx] = src[(size_t)(k0 + ty) * 256 + n0 + tx];
        }
        __syncthreads();
        #pragma unroll
        for (int it = 0; it < 8; it++) {
            int lt_g = base + it;
            u16* dst; int K, lt;
            if (lt_g < 32)       { dst = outT;  K = 128; lt = lt_g; }
            else if (lt_g < 64)  { dst = bandT; K = 128; lt = lt_g - 32; }
            else if (lt_g < 192) { dst = modT;  K = 512; lt = lt_g - 64; }
            else                 { dst = hvT;   K = 256; lt = lt_g - 192; }
            int tk = K >> 5;
            int k0 = (lt % tk) * 32, n0 = (lt / tk) * 32;
            dst[wtile(n0 + ty, k0 + tx, K)] = f2bf(sm.tr.tile[it][tx][ty]);
        }
    } else {
        // ---- sort path: counting sort by window start; wave-shuffle scan ----
        int gD = gDp[0], gH = gHp[0], gW = gWp[0], gT = gTp[0];
        int Ng = gD * gH * gW * gT;
        sm.so.hist[t] = 0;
        __syncthreads();
        int sarr[4];
        #pragma unroll
        for (int i = 0; i < 4; i++) {
            int q = i * 1024 + t;
            float4 xv = *(const float4*)&x[q * 4];
            int zi = (int)(xv.x * (float)gD);
            int yi = (int)(xv.y * (float)gH);
            int xi = (int)(xv.z * (float)gW);
            int ti = (int)(xv.w * (float)gT);
            int idx = ((ti * gD + zi) * gH + yi) * gW + xi;
            float tt = (float)idx / (float)Ng;
            int s = (int)ceilf(tt * (float)LN - ((float)(TOPKN / 2) + 0.5f));
            s = min(max(s, 0), LN - TOPKN);
            sarr[i] = s;
            atomicAdd(&sm.so.hist[s], 1);
        }
        __syncthreads();
        int cnt = sm.so.hist[t];
        int incl = cnt;
        #pragma unroll
        for (int off = 1; off < 64; off <<= 1) {
            int u = __shfl_up(incl, off);
            if (lane >= off) incl += u;
        }
        if (lane == 63) sm.so.cur[wid] = incl;
        __syncthreads();
        if (wid == 0) {
            int v = (lane < 16) ? sm.so.cur[lane] : 0;
            #pragma unroll
            for (int off = 1; off < 16; off <<= 1) {
                int u = __shfl_up(v, off);
                if (lane >= off) v += u;
            }
            if (lane < 16) sm.so.cur[lane] = v;
        }
        __syncthreads();
        int woff = wid ? sm.so.cur[wid - 1] : 0;
        sm.so.hist[t] = woff + incl - cnt;   // exclusive offset → placement cursor
        __syncthreads();
        #pragma unroll
        for (int i = 0; i < 4; i++) {
            int q = i * 1024 + t;
            int pos = atomicAdd(&sm.so.hist[sarr[i]], 1);
            perm[pos] = q;
            ssort[pos] = sarr[i];
        }
    }
}

// ---------------------------------------------------------------------------
// Launch 2: fused. 256 blocks x 1024 threads, 1 block/CU. 32 SORTED queries
// of one batch per block -> every weight fragment read serves 32 rows
// (weight L2 traffic halved vs 512x16). MLP runs M=32 (2 A-frags / B-frag).
// ---------------------------------------------------------------------------
__global__ __launch_bounds__(1024, 4) void fused_kernel(
    const float* __restrict__ x,
    const u16* __restrict__ kbf, const u16* __restrict__ vtbf,
    const u16* __restrict__ qall,
    const int* __restrict__ perm, const int* __restrict__ ssort,
    const u16* __restrict__ outT, const float* __restrict__ out_b,
    const u16* __restrict__ bandT, const float* __restrict__ band_b,
    const u16* __restrict__ modT, const float* __restrict__ mod_b,
    const u16* __restrict__ hvT, const float* __restrict__ hv_b,
    const float* __restrict__ outl_W, const float* __restrict__ outl_b,
    float* __restrict__ out)
{
    const int bid = blockIdx.x;
    const int b   = bid >> 7;            // batch
    const int g0  = (bid & 127) * 32;    // 32-query sorted group
    const int t   = threadIdx.x;
    const int wid = t >> 6, lane = t & 63;
    const int quad = lane >> 4, l16 = lane & 15;

    __shared__ __align__(16) u16 q_bf[32 * 136];
    __shared__ __align__(16) u16 gam_lds[64 * 72];
    __shared__ __align__(16) float scores32[64 * PFP];   // scores / P_bf / modu+s01
    __shared__ __align__(16) u16 o_lds[32 * 136];
    __shared__ float fin[16 * 32];
    __shared__ float sh_xc[128];
    __shared__ int sh_pq[32], sh_s[32];

    u16* modu_lds = (u16*)scores32;                  // 32 x 264
    u16* s01_lds  = ((u16*)scores32) + 32 * 264;     // 32 x 264

    if (t < 32) { sh_pq[t] = perm[g0 + t]; sh_s[t] = ssort[g0 + t]; }
    __syncthreads();                                             // b1

    {   // stage q: 32 rows x 128 bf16; 1024 threads x 8B
        int m = t >> 5, d = (t & 31) * 4;
        *(uint2*)&q_bf[m * 136 + d] = *(const uint2*)&qall[(size_t)sh_pq[m] * 128 + d];
    }
    if (t < 128) sh_xc[t] = x[(size_t)sh_pq[t >> 2] * 4 + (t & 3)];
    __syncthreads();                                             // b2

    // layer gammas: 64 rows (2 layers x 32 queries) x 64 entries; 4/thread
    #pragma unroll
    for (int j = 0; j < 4; j++) {
        int e = j * 1024 + t;
        int l = e >> 11, g = (e >> 6) & 31, f = e & 63;
        int c = f >> 4, jj = f & 15, oi = jj & 7;
        float om = 10.0f * exp2f((float)oi * (l ? LOG2R1 : LOG2R0));
        float arg = PI_F * sh_xc[g * 4 + c] * om;
        gam_lds[(l * 32 + g) * 72 + f] = f2bf((jj < 8) ? __sinf(arg) : __cosf(arg));
    }

    const int u0    = sh_s[0] & ~15;           // 16-aligned for K tiling
    const int ncols = min((sh_s[31] + 128 - u0 + 31) & ~31, NCMAX);
    const int nsub  = ncols >> 4;
    const int nkc   = ncols >> 5;

    // ---- scores, both heads, 32 q-rows: job = (head, subtile), 2 accs/job ----
    {
        s16x8 aq[2][4];
        #pragma unroll
        for (int rh = 0; rh < 2; rh++)
            #pragma unroll
            for (int c = 0; c < 4; c++)
                aq[rh][c] = *(const s16x8*)&q_bf[(rh * 16 + l16) * 136 + c * 32 + quad * 8];
        for (int j = wid; j < 2 * nsub; j += 16) {
            int h = (j >= nsub) ? 1 : 0;
            int sub = j - h * nsub;
            int lrow = u0 + sub * 16 + l16;
            f32x4 acc0 = (f32x4){0.f, 0.f, 0.f, 0.f};
            f32x4 acc1 = (f32x4){0.f, 0.f, 0.f, 0.f};
            s16x8 b0 = *(const s16x8*)&kbf[kidx(b, lrow, h * 64 + quad * 8)];
            s16x8 b1 = *(const s16x8*)&kbf[kidx(b, lrow, h * 64 + 32 + quad * 8)];
            acc0 = __builtin_amdgcn_mfma_f32_16x16x32_bf16(aq[0][h * 2 + 0], b0, acc0, 0, 0, 0);
            acc0 = __builtin_amdgcn_mfma_f32_16x16x32_bf16(aq[0][h * 2 + 1], b1, acc0, 0, 0, 0);
            acc1 = __builtin_amdgcn_mfma_f32_16x16x32_bf16(aq[1][h * 2 + 0], b0, acc1, 0, 0, 0);
            acc1 = __builtin_amdgcn_mfma_f32_16x16x32_bf16(aq[1][h * 2 + 1], b1, acc1, 0, 0, 0);
            #pragma unroll
            for (int r = 0; r < 4; r++) {
                scores32[(h * 32 + quad * 4 + r) * PFP + sub * 16 + l16] = acc0[r];
                scores32[(h * 32 + 16 + quad * 4 + r) * PFP + sub * 16 + l16] = acc1[r];
            }
        }
    }
    __syncthreads();                                             // b3

    // ---- masked softmax: 64 rows, 4 rows/wave; bf16 P written in-place ----
    {
        #pragma unroll
        for (int rr = 0; rr < 4; rr++) {
            int row = wid + rr * 16;            // 0..63
            int qq  = row & 31;
            int sg  = sh_s[qq];
            float vals[6]; int ok[6];
            float mx = -1e30f;
            #pragma unroll
            for (int i = 0; i < 6; i++) {
                int c = lane + 64 * i;
                float v = scores32[row * PFP + c] * 0.125f;
                int key = u0 + c;
                int o2 = (c < ncols) && (key >= sg) && (key < sg + 128);
                vals[i] = v; ok[i] = o2;
                if (o2) mx = fmaxf(mx, v);
            }
            #pragma unroll
            for (int off = 1; off < 64; off <<= 1) mx = fmaxf(mx, __shfl_xor(mx, off));
            float sum = 0.f, e6[6];
            #pragma unroll
            for (int i = 0; i < 6; i++) {
                float e = ok[i] ? __expf(vals[i] - mx) : 0.f;
                e6[i] = e; sum += e;
            }
            #pragma unroll
            for (int off = 1; off < 64; off <<= 1) sum += __shfl_xor(sum, off);
            float inv = 1.f / sum;
            u16* prow = (u16*)&scores32[row * PFP];   // in-place bf16 P (row-local)
            #pragma unroll
            for (int i = 0; i < 6; i++) {
                int c = lane + 64 * i;
                if (c < ncols) prow[c] = f2bf(e6[i] * inv);
            }
        }
    }
    __syncthreads();                                             // b4

    // ---- P @ V (MFMA): 16 waves = (col-tile, row-half) ----
    {
        int ct = wid & 7, rh = wid >> 3;
        int h = ct >> 2;
        const u16* prow = (const u16*)&scores32[(h * 32 + rh * 16 + l16) * PFP];
        f32x4 acc = (f32x4){0.f, 0.f, 0.f, 0.f};
        #pragma unroll 2
        for (int kc = 0; kc < nkc; kc++) {
            s16x8 a = *(const s16x8*)&prow[kc * 32 + quad * 8];
            int koff = u0 + kc * 32 + quad * 8;
            koff = min(koff, 1016);   // OOB chunks: P=0 there, V stays valid
            s16x8 bfr = *(const s16x8*)&vtbf[vidx(b, ct * 16 + l16, koff)];
            acc = __builtin_amdgcn_mfma_f32_16x16x32_bf16(a, bfr, acc, 0, 0, 0);
        }
        #pragma unroll
        for (int r = 0; r < 4; r++)
            o_lds[(rh * 16 + quad * 4 + r) * 136 + ct * 16 + l16] = f2bf(acc[r]);
    }
    __syncthreads();                                             // b5

    // ---------------- MFMA MLP: 16 waves x 16 cols, M=32 ----------------
    const int n0 = wid * 16;
    float m0f[2][4];

    {   // modulation = o @ out_W + out_b (K=128)
        f32x4 am0 = (f32x4){0.f, 0.f, 0.f, 0.f};
        f32x4 am1 = (f32x4){0.f, 0.f, 0.f, 0.f};
        #pragma unroll
        for (int kc = 0; kc < 4; kc++) {
            s16x8 bfr = *(const s16x8*)&outT[wtile(n0 + l16, kc * 32 + quad * 8, 128)];
            s16x8 a0 = *(const s16x8*)&o_lds[l16 * 136 + kc * 32 + quad * 8];
            s16x8 a1 = *(const s16x8*)&o_lds[(16 + l16) * 136 + kc * 32 + quad * 8];
            am0 = __builtin_amdgcn_mfma_f32_16x16x32_bf16(a0, bfr, am0, 0, 0, 0);
            am1 = __builtin_amdgcn_mfma_f32_16x16x32_bf16(a1, bfr, am1, 0, 0, 0);
        }
        int col = n0 + l16;
        float bias = out_b[col];
        #pragma unroll
        for (int r = 0; r < 4; r++) {
            modu_lds[(quad * 4 + r) * 264 + col] = f2bf(am0[r] + bias);
            modu_lds[(16 + quad * 4 + r) * 264 + col] = f2bf(am1[r] + bias);
        }
    }
    __syncthreads();                                             // b6

    #pragma unroll
    for (int l = 0; l < 2; l++) {
        f32x4 ab0 = (f32x4){0.f, 0.f, 0.f, 0.f};
        f32x4 ab1 = (f32x4){0.f, 0.f, 0.f, 0.f};
        f32x4 am0 = (f32x4){0.f, 0.f, 0.f, 0.f};
        f32x4 am1 = (f32x4){0.f, 0.f, 0.f, 0.f};
        #pragma unroll
        for (int kc = 0; kc < 2; kc++) {
            s16x8 bfr = *(const s16x8*)&bandT[wtile(n0 + l16, l * 64 + kc * 32 + quad * 8, 128)];
            s16x8 a0 = *(const s16x8*)&gam_lds[(l * 32 + l16) * 72 + kc * 32 + quad * 8];
            s16x8 a1 = *(const s16x8*)&gam_lds[(l * 32 + 16 + l16) * 72 + kc * 32 + quad * 8];
            ab0 = __builtin_amdgcn_mfma_f32_16x16x32_bf16(a0, bfr, ab0, 0, 0, 0);
            ab1 = __builtin_amdgcn_mfma_f32_16x16x32_bf16(a1, bfr, ab1, 0, 0, 0);
        }
        #pragma unroll
        for (int kc = 0; kc < 8; kc++) {
            s16x8 bfr = *(const s16x8*)&modT[wtile(n0 + l16, l * 256 + kc * 32 + quad * 8, 512)];
            s16x8 a0 = *(const s16x8*)&modu_lds[l16 * 264 + kc * 32 + quad * 8];
            s16x8 a1 = *(const s16x8*)&modu_lds[(16 + l16) * 264 + kc * 32 + quad * 8];
            am0 = __builtin_amdgcn_mfma_f32_16x16x32_bf16(a0, bfr, am0, 0, 0, 0);
            am1 = __builtin_amdgcn_mfma_f32_16x16x32_bf16(a1, bfr, am1, 0, 0, 0);
        }
        int col = n0 + l16;
        float bb = band_b[l * 256 + col];
        float mb = mod_b[l * 256 + col];
        #pragma unroll
        for (int r = 0; r < 4; r++) {
            float h0 = fmaxf(ab0[r] + bb, 0.f);
            float v0 = fmaxf(h0 + am0[r] + mb, 0.f);
            float h1 = fmaxf(ab1[r] + bb, 0.f);
            float v1 = fmaxf(h1 + am1[r] + mb, 0.f);
            if (l == 0) { m0f[0][r] = v0; m0f[1][r] = v1; }
            else {
                s01_lds[(quad * 4 + r) * 264 + col] = f2bf(m0f[0][r] + v0);
                s01_lds[(16 + quad * 4 + r) * 264 + col] = f2bf(m0f[1][r] + v1);
            }
        }
    }
    __syncthreads();                                             // b7

    {   // h_v1 = relu(s01 @ hv_W + hv_b) + scalar head
        f32x4 ah0 = (f32x4){0.f, 0.f, 0.f, 0.f};
        f32x4 ah1 = (f32x4){0.f, 0.f, 0.f, 0.f};
        #pragma unroll
        for (int kc = 0; kc < 8; kc++) {
            s16x8 bfr = *(const s16x8*)&hvT[wtile(n0 + l16, kc * 32 + quad * 8, 256)];
            s16x8 a0 = *(const s16x8*)&s01_lds[l16 * 264 + kc * 32 + quad * 8];
            s16x8 a1 = *(const s16x8*)&s01_lds[(16 + l16) * 264 + kc * 32 + quad * 8];
            ah0 = __builtin_amdgcn_mfma_f32_16x16x32_bf16(a0, bfr, ah0, 0, 0, 0);
            ah1 = __builtin_amdgcn_mfma_f32_16x16x32_bf16(a1, bfr, ah1, 0, 0, 0);
        }
        int col = n0 + l16;
        float w0 = outl_W[col], w1 = outl_W[256 + col], hb = hv_b[col];
        #pragma unroll
        for (int r = 0; r < 4; r++) {
            float pv0 = m0f[0][r] * w0 + fmaxf(ah0[r] + hb, 0.f) * w1;
            float pv1 = m0f[1][r] * w0 + fmaxf(ah1[r] + hb, 0.f) * w1;
            #pragma unroll
            for (int off = 1; off < 16; off <<= 1) {
                pv0 += __shfl_xor(pv0, off);
                pv1 += __shfl_xor(pv1, off);
            }
            if (l16 == 0) {
                fin[wid * 32 + quad * 4 + r] = pv0;
                fin[wid * 32 + 16 + quad * 4 + r] = pv1;
            }
        }
    }
    __syncthreads();                                             // b8
    if (t < 32) {
        float s2 = outl_b[0] + outl_b[1];
        #pragma unroll
        for (int w = 0; w < 16; w++) s2 += fin[w * 32 + t];
        out[(size_t)b * QN + sh_pq[t]] = s2;   // scatter by permutation
    }
}

// ---------------------------------------------------------------------------
extern "C" void kernel_launch(void* const* d_in, const int* in_sizes, int n_in,
                              void* d_out, int out_size, void* d_ws, size_t ws_size,
                              hipStream_t stream)
{
    const float* x       = (const float*)d_in[0];
    const float* tokens  = (const float*)d_in[1];
    const float* query_W = (const float*)d_in[2];
    const float* query_b = (const float*)d_in[3];
    const float* q_W     = (const float*)d_in[4];
    const float* kv_W    = (const float*)d_in[5];
    const float* out_W   = (const float*)d_in[6];
    const float* out_b   = (const float*)d_in[7];
    const float* band_W  = (const float*)d_in[8];
    const float* band_b  = (const float*)d_in[9];
    const float* mod_W   = (const float*)d_in[10];
    const float* mod_b   = (const float*)d_in[11];
    const float* hv_W    = (const float*)d_in[12];
    const float* hv_b    = (const float*)d_in[13];
    const float* outl_W  = (const float*)d_in[14];
    const float* outl_b  = (const float*)d_in[15];
    const int*   gD      = (const int*)d_in[16];
    const int*   gH      = (const int*)d_in[17];
    const int*   gW      = (const int*)d_in[18];
    const int*   gT      = (const int*)d_in[19];

    float* ws   = (float*)d_ws;
    u16* qall   = (u16*)ws;                         // 4096*128 bf16
    u16* wb = (u16*)(ws + 524288);
    u16* kbf   = wb;                                // 2*1024*128 bf16 (tiled)
    u16* vtbf  = wb + 262144;                       // 2*128*1024 bf16 (tiled)
    u16* outT  = wb + 524288;                       // 32768 (tiled)
    u16* bandT = wb + 557056;                       // 32768 (tiled)
    u16* modT  = wb + 589824;                       // 131072 (tiled)
    u16* hvT   = wb + 720896;                       // 65536 (tiled)
    int* perm  = (int*)(wb + 786432);               // 4096 ints
    int* ssort = perm + 4096;                       // 4096 ints
    float* out = (float*)d_out;

    prep_kernel<<<225, 1024, 0, stream>>>(tokens, kv_W, x, query_W, query_b, q_W,
                                          out_W, band_W, mod_W, hv_W,
                                          gD, gH, gW, gT,
                                          qall, kbf, vtbf, outT, bandT, modT, hvT,
                                          perm, ssort);
    fused_kernel<<<256, 1024, 0, stream>>>(x, kbf, vtbf, qall, perm, ssort,
        outT, out_b, bandT, band_b, modT, mod_b, hvT, hv_b,
        outl_W, outl_b, out);
}

// Round 4
// 120.027 us; speedup vs baseline: 1.0724x; 1.0128x over previous
//
#include <hip/hip_runtime.h>
#include <math.h>

// Problem constants (match reference setup_inputs)
#define BN     2
#define QN     4096
#define LN     1024
#define TOPKN  128
#define PI_F   3.14159265358979323846f

// log2 of the per-step omega ratio: omegas = 10 * 2^(i*LOG2R)
// LOG2R0 = log2(12.8)/7, LOG2R1 = log2(3.2)/7
#define LOG2R0 0.52543879f
#define LOG2R1 0.23972456f

// union-window capacity (keys) for a 32-query sorted group, and padded pitch.
// PFP=388: 388 mod 32 = 4 -> 16 consecutive rows spread over 8 banks (2-way, free)
#define NCMAX  384
#define PFP    388

typedef __attribute__((ext_vector_type(8))) short  s16x8;
typedef __attribute__((ext_vector_type(4))) short  s16x4;
typedef __attribute__((ext_vector_type(4))) float  f32x4;
typedef unsigned short u16;

__device__ __forceinline__ u16 f2bf(float f) {
    unsigned int u = __float_as_uint(f);
    u = (u + 0x7FFFu + ((u >> 16) & 1u)) >> 16;   // RNE
    return (u16)u;
}

// Build a 16x16x32 B-fragment directly from fp32 row-major global memory.
__device__ __forceinline__ s16x8 ldB(const float* __restrict__ base, int stride) {
    s16x8 r;
    #pragma unroll
    for (int jj = 0; jj < 8; jj++) r[jj] = (short)f2bf(base[(size_t)jj * stride]);
    return r;
}

// Tiled B-operand layouts: one wave MFMA-fragment load = contiguous memory.
// Weights wT: [n/16][k/32][n%16][k%32]  (wave load spans 1024B contiguous)
__device__ __forceinline__ size_t wtile(int n, int k, int K) {
    return (size_t)((n >> 4) * (K >> 5) + (k >> 5)) * 512 + (n & 15) * 32 + (k & 31);
}
// K cache: [b][l/16][d/8][l%16][d%8]  (256B contiguous per quad)
__device__ __forceinline__ size_t kidx(int b, int l, int d) {
    return (((size_t)(b * 64 + (l >> 4)) * 16 + (d >> 3)) * 16 + (l & 15)) * 8 + (d & 7);
}
// V cache: [b][n/16][k/8][n%16][k%8]  (256B contiguous per quad)
__device__ __forceinline__ size_t vidx(int b, int n, int k) {
    return (((size_t)(b * 8 + (n >> 4)) * 128 + (k >> 3)) * 16 + (n & 15)) * 8 + (k & 7);
}

// ---------------------------------------------------------------------------
// Launch 1: prep, 225 blocks x 1024 threads (unchanged from round 3).
// ---------------------------------------------------------------------------
struct KvS { u16 tok[32 * 264]; };
struct QS  { float shx[128]; u16 gam[32 * 72]; u16 xq[32 * 264]; };
struct TrS { float tile[8][32][33]; };
struct SoS { int hist[1024]; int cur[1024]; };
union PrepS { KvS kv; QS q; TrS tr; SoS so; };

__global__ __launch_bounds__(1024) void prep_kernel(
    const float* __restrict__ tokens, const float* __restrict__ kv_W,
    const float* __restrict__ x, const float* __restrict__ query_W,
    const float* __restrict__ query_b, const float* __restrict__ q_W,
    const float* __restrict__ outW, const float* __restrict__ bandW,
    const float* __restrict__ modW, const float* __restrict__ hvW,
    const int* __restrict__ gDp, const int* __restrict__ gHp,
    const int* __restrict__ gWp, const int* __restrict__ gTp,
    u16* __restrict__ qall, u16* __restrict__ kbf, u16* __restrict__ vtbf,
    u16* __restrict__ outT, u16* __restrict__ bandT,
    u16* __restrict__ modT, u16* __restrict__ hvT,
    int* __restrict__ perm, int* __restrict__ ssort)
{
    __shared__ __align__(16) PrepS sm;
    const int bid = blockIdx.x;
    const int t   = threadIdx.x;
    const int wid = t >> 6, lane = t & 63;
    const int quad = lane >> 4, l16 = lane & 15;

    if (bid < 64) {
        // ---- kv path: 32 token rows/block, 16 waves, single barrier ----
        int l0 = bid * 32;
        int b = l0 >> 10, lloc = l0 & 1023;
        #pragma unroll
        for (int i = 0; i < 8; i++) {
            int idx = i * 1024 + t; int row = idx >> 8, col = idx & 255;
            sm.kv.tok[row * 264 + col] = f2bf(tokens[(size_t)(l0 + row) * 256 + col]);
        }
        __syncthreads();
        int m0 = (wid & 1) * 16;
        int c0 = (wid >> 1) * 32;
        f32x4 acc[2];
        acc[0] = (f32x4){0.f, 0.f, 0.f, 0.f};
        acc[1] = (f32x4){0.f, 0.f, 0.f, 0.f};
        for (int kc = 0; kc < 8; kc++) {
            s16x8 a = *(const s16x8*)&sm.kv.tok[(m0 + l16) * 264 + kc * 32 + quad * 8];
            #pragma unroll
            for (int sub = 0; sub < 2; sub++) {
                s16x8 bfr = ldB(&kv_W[(size_t)(kc * 32 + quad * 8) * 256 + c0 + sub * 16 + l16], 256);
                acc[sub] = __builtin_amdgcn_mfma_f32_16x16x32_bf16(a, bfr, acc[sub], 0, 0, 0);
            }
        }
        #pragma unroll
        for (int sub = 0; sub < 2; sub++) {
            int col = c0 + sub * 16 + l16;
            if (col < 128) {
                #pragma unroll
                for (int r = 0; r < 4; r++)
                    kbf[kidx(b, lloc + m0 + quad * 4 + r, col)] = f2bf(acc[sub][r]);
            } else {
                s16x4 pk;
                pk[0] = (short)f2bf(acc[sub][0]); pk[1] = (short)f2bf(acc[sub][1]);
                pk[2] = (short)f2bf(acc[sub][2]); pk[3] = (short)f2bf(acc[sub][3]);
                *(s16x4*)&vtbf[vidx(b, col - 128, lloc + m0 + quad * 4)] = pk;
            }
        }
    } else if (bid < 192) {
        // ---- q path: 32 queries/block, 16 waves, 3 barriers ----
        int p0 = (bid - 64) * 32;
        if (t < 128) sm.q.shx[t] = x[p0 * 4 + t];
        __syncthreads();
        #pragma unroll
        for (int j = 0; j < 2; j++) {
            int e = t * 2 + j;
            int g = e >> 6, f = e & 63;
            int c = f >> 4, jj = f & 15, oi = jj & 7;
            float om = 10.0f * exp2f((float)oi * LOG2R0);
            float arg = PI_F * sm.q.shx[g * 4 + c] * om;
            sm.q.gam[g * 72 + f] = f2bf((jj < 8) ? __sinf(arg) : __cosf(arg));
        }
        __syncthreads();
        int m0 = (wid & 1) * 16;
        {   // stage 1: xq = relu(gamma @ query_W + b), B direct from global
            int c0 = (wid >> 1) * 32;
            f32x4 acc[2];
            acc[0] = (f32x4){0.f, 0.f, 0.f, 0.f};
            acc[1] = (f32x4){0.f, 0.f, 0.f, 0.f};
            for (int kc = 0; kc < 2; kc++) {
                s16x8 a = *(const s16x8*)&sm.q.gam[(m0 + l16) * 72 + kc * 32 + quad * 8];
                #pragma unroll
                for (int sub = 0; sub < 2; sub++) {
                    s16x8 bfr = ldB(&query_W[(size_t)(kc * 32 + quad * 8) * 256 + c0 + sub * 16 + l16], 256);
                    acc[sub] = __builtin_amdgcn_mfma_f32_16x16x32_bf16(a, bfr, acc[sub], 0, 0, 0);
                }
            }
            #pragma unroll
            for (int sub = 0; sub < 2; sub++) {
                int col = c0 + sub * 16 + l16;
                float bias = query_b[col];
                #pragma unroll
                for (int r = 0; r < 4; r++)
                    sm.q.xq[(m0 + quad * 4 + r) * 264 + col] = f2bf(fmaxf(acc[sub][r] + bias, 0.f));
            }
        }
        __syncthreads();
        {   // stage 2: q = xq @ q_W (bf16 out), B direct from global
            int n0q = (wid >> 1) * 16;
            f32x4 acc2 = (f32x4){0.f, 0.f, 0.f, 0.f};
            for (int kc = 0; kc < 8; kc++) {
                s16x8 a = *(const s16x8*)&sm.q.xq[(m0 + l16) * 264 + kc * 32 + quad * 8];
                s16x8 bfr = ldB(&q_W[(size_t)(kc * 32 + quad * 8) * 128 + n0q + l16], 128);
                acc2 = __builtin_amdgcn_mfma_f32_16x16x32_bf16(a, bfr, acc2, 0, 0, 0);
            }
            #pragma unroll
            for (int r = 0; r < 4; r++)
                qall[(size_t)(p0 + m0 + quad * 4 + r) * 128 + n0q + l16] = f2bf(acc2[r]);
        }
    } else if (bid < 224) {
        // ---- transpose path: 8 32x32 tiles/block, all staged at once ----
        int base = (bid - 192) * 8;
        int tx = t & 31, ty = (t >> 5) & 31;
        #pragma unroll
        for (int it = 0; it < 8; it++) {
            int lt_g = base + it;
            const float* src; int K, lt;
            if (lt_g < 32)       { src = outW;  K = 128; lt = lt_g; }
            else if (lt_g < 64)  { src = bandW; K = 128; lt = lt_g - 32; }
            else if (lt_g < 192) { src = modW;  K = 512; lt = lt_g - 64; }
            else                 { src = hvW;   K = 256; lt = lt_g - 192; }
            int tk = K >> 5;
            int k0 = (lt % tk) * 32, n0 = (lt / tk) * 32;
            sm.tr.tile[it][ty][tx] = src[(size_t)(k0 + ty) * 256 + n0 + tx];
        }
        __syncthreads();
        #pragma unroll
        for (int it = 0; it < 8; it++) {
            int lt_g = base + it;
            u16* dst; int K, lt;
            if (lt_g < 32)       { dst = outT;  K = 128; lt = lt_g; }
            else if (lt_g < 64)  { dst = bandT; K = 128; lt = lt_g - 32; }
            else if (lt_g < 192) { dst = modT;  K = 512; lt = lt_g - 64; }
            else                 { dst = hvT;   K = 256; lt = lt_g - 192; }
            int tk = K >> 5;
            int k0 = (lt % tk) * 32, n0 = (lt / tk) * 32;
            dst[wtile(n0 + ty, k0 + tx, K)] = f2bf(sm.tr.tile[it][tx][ty]);
        }
    } else {
        // ---- sort path: counting sort by window start; wave-shuffle scan ----
        int gD = gDp[0], gH = gHp[0], gW = gWp[0], gT = gTp[0];
        int Ng = gD * gH * gW * gT;
        sm.so.hist[t] = 0;
        __syncthreads();
        int sarr[4];
        #pragma unroll
        for (int i = 0; i < 4; i++) {
            int q = i * 1024 + t;
            float4 xv = *(const float4*)&x[q * 4];
            int zi = (int)(xv.x * (float)gD);
            int yi = (int)(xv.y * (float)gH);
            int xi = (int)(xv.z * (float)gW);
            int ti = (int)(xv.w * (float)gT);
            int idx = ((ti * gD + zi) * gH + yi) * gW + xi;
            float tt = (float)idx / (float)Ng;
            int s = (int)ceilf(tt * (float)LN - ((float)(TOPKN / 2) + 0.5f));
            s = min(max(s, 0), LN - TOPKN);
            sarr[i] = s;
            atomicAdd(&sm.so.hist[s], 1);
        }
        __syncthreads();
        int cnt = sm.so.hist[t];
        int incl = cnt;
        #pragma unroll
        for (int off = 1; off < 64; off <<= 1) {
            int u = __shfl_up(incl, off);
            if (lane >= off) incl += u;
        }
        if (lane == 63) sm.so.cur[wid] = incl;
        __syncthreads();
        if (wid == 0) {
            int v = (lane < 16) ? sm.so.cur[lane] : 0;
            #pragma unroll
            for (int off = 1; off < 16; off <<= 1) {
                int u = __shfl_up(v, off);
                if (lane >= off) v += u;
            }
            if (lane < 16) sm.so.cur[lane] = v;
        }
        __syncthreads();
        int woff = wid ? sm.so.cur[wid - 1] : 0;
        sm.so.hist[t] = woff + incl - cnt;   // exclusive offset → placement cursor
        __syncthreads();
        #pragma unroll
        for (int i = 0; i < 4; i++) {
            int q = i * 1024 + t;
            int pos = atomicAdd(&sm.so.hist[sarr[i]], 1);
            perm[pos] = q;
            ssort[pos] = sarr[i];
        }
    }
}

// ---------------------------------------------------------------------------
// Launch 2: fused. 256 blocks x 1024 threads. 32 sorted queries per block.
// Latency-hiding: V-frags (6) + kbf job1 prefetched right after b1; wout
// prefetched after b4; band GEMM hoisted before b6 (depends only on gammas).
// ---------------------------------------------------------------------------
__global__ __launch_bounds__(1024, 4) void fused_kernel(
    const float* __restrict__ x,
    const u16* __restrict__ kbf, const u16* __restrict__ vtbf,
    const u16* __restrict__ qall,
    const int* __restrict__ perm, const int* __restrict__ ssort,
    const u16* __restrict__ outT, const float* __restrict__ out_b,
    const u16* __restrict__ bandT, const float* __restrict__ band_b,
    const u16* __restrict__ modT, const float* __restrict__ mod_b,
    const u16* __restrict__ hvT, const float* __restrict__ hv_b,
    const float* __restrict__ outl_W, const float* __restrict__ outl_b,
    float* __restrict__ out)
{
    const int bid = blockIdx.x;
    const int b   = bid >> 7;            // batch
    const int g0  = (bid & 127) * 32;    // 32-query sorted group
    const int t   = threadIdx.x;
    const int wid = t >> 6, lane = t & 63;
    const int quad = lane >> 4, l16 = lane & 15;

    __shared__ __align__(16) u16 q_bf[32 * 136];
    __shared__ __align__(16) u16 gam_lds[64 * 72];
    __shared__ __align__(16) float scores32[64 * PFP];   // scores / P_bf / modu+s01
    __shared__ __align__(16) u16 o_lds[32 * 136];
    __shared__ float fin[16 * 32];
    __shared__ float sh_xc[128];
    __shared__ int sh_pq[32], sh_s[32];

    u16* modu_lds = (u16*)scores32;                  // 32 x 264
    u16* s01_lds  = ((u16*)scores32) + 32 * 264;     // 32 x 264

    if (t < 32) { sh_pq[t] = perm[g0 + t]; sh_s[t] = ssort[g0 + t]; }
    __syncthreads();                                             // b1

    const int u0    = sh_s[0] & ~15;           // 16-aligned for K tiling
    const int ncols = min((sh_s[31] + 128 - u0 + 31) & ~31, NCMAX);
    const int nsub  = ncols >> 4;
    const int nkc   = ncols >> 5;

    // ---- V prefetch: 6 fragments for PV; depends only on u0/b/wid ----
    const int ct = wid & 7, rh = wid >> 3;
    s16x8 vf[6];
    #pragma unroll
    for (int kc = 0; kc < 6; kc++) {
        int koff = min(u0 + kc * 32 + quad * 8, 1016);
        vf[kc] = *(const s16x8*)&vtbf[vidx(b, ct * 16 + l16, koff)];
    }
    // ---- kbf job-1 prefetch (job wid is always valid: 2*nsub >= 16) ----
    const int h1   = (wid >= nsub) ? 1 : 0;
    const int sub1 = wid - h1 * nsub;
    const int lrow1 = u0 + sub1 * 16 + l16;
    s16x8 kb0 = *(const s16x8*)&kbf[kidx(b, lrow1, h1 * 64 + quad * 8)];
    s16x8 kb1 = *(const s16x8*)&kbf[kidx(b, lrow1, h1 * 64 + 32 + quad * 8)];

    {   // stage q: 32 rows x 128 bf16; 1024 threads x 8B
        int m = t >> 5, d = (t & 31) * 4;
        *(uint2*)&q_bf[m * 136 + d] = *(const uint2*)&qall[(size_t)sh_pq[m] * 128 + d];
    }
    if (t < 128) sh_xc[t] = x[(size_t)sh_pq[t >> 2] * 4 + (t & 3)];
    __syncthreads();                                             // b2

    // layer gammas: VALU block placed between load-issue and MFMA-consume
    #pragma unroll
    for (int j = 0; j < 4; j++) {
        int e = j * 1024 + t;
        int l = e >> 11, g = (e >> 6) & 31, f = e & 63;
        int c = f >> 4, jj = f & 15, oi = jj & 7;
        float om = 10.0f * exp2f((float)oi * (l ? LOG2R1 : LOG2R0));
        float arg = PI_F * sh_xc[g * 4 + c] * om;
        gam_lds[(l * 32 + g) * 72 + f] = f2bf((jj < 8) ? __sinf(arg) : __cosf(arg));
    }

    // ---- scores, both heads, 32 q-rows: job = (head, subtile), 2 accs/job ----
    {
        s16x8 aq[2][4];
        #pragma unroll
        for (int rh2 = 0; rh2 < 2; rh2++)
            #pragma unroll
            for (int c = 0; c < 4; c++)
                aq[rh2][c] = *(const s16x8*)&q_bf[(rh2 * 16 + l16) * 136 + c * 32 + quad * 8];
        {   // job 1 from prefetched fragments
            f32x4 acc0 = (f32x4){0.f, 0.f, 0.f, 0.f};
            f32x4 acc1 = (f32x4){0.f, 0.f, 0.f, 0.f};
            acc0 = __builtin_amdgcn_mfma_f32_16x16x32_bf16(aq[0][h1 * 2 + 0], kb0, acc0, 0, 0, 0);
            acc0 = __builtin_amdgcn_mfma_f32_16x16x32_bf16(aq[0][h1 * 2 + 1], kb1, acc0, 0, 0, 0);
            acc1 = __builtin_amdgcn_mfma_f32_16x16x32_bf16(aq[1][h1 * 2 + 0], kb0, acc1, 0, 0, 0);
            acc1 = __builtin_amdgcn_mfma_f32_16x16x32_bf16(aq[1][h1 * 2 + 1], kb1, acc1, 0, 0, 0);
            #pragma unroll
            for (int r = 0; r < 4; r++) {
                scores32[(h1 * 32 + quad * 4 + r) * PFP + sub1 * 16 + l16] = acc0[r];
                scores32[(h1 * 32 + 16 + quad * 4 + r) * PFP + sub1 * 16 + l16] = acc1[r];
            }
        }
        for (int j = wid + 16; j < 2 * nsub; j += 16) {
            int h = (j >= nsub) ? 1 : 0;
            int sub = j - h * nsub;
            int lrow = u0 + sub * 16 + l16;
            f32x4 acc0 = (f32x4){0.f, 0.f, 0.f, 0.f};
            f32x4 acc1 = (f32x4){0.f, 0.f, 0.f, 0.f};
            s16x8 b0 = *(const s16x8*)&kbf[kidx(b, lrow, h * 64 + quad * 8)];
            s16x8 b1 = *(const s16x8*)&kbf[kidx(b, lrow, h * 64 + 32 + quad * 8)];
            acc0 = __builtin_amdgcn_mfma_f32_16x16x32_bf16(aq[0][h * 2 + 0], b0, acc0, 0, 0, 0);
            acc0 = __builtin_amdgcn_mfma_f32_16x16x32_bf16(aq[0][h * 2 + 1], b1, acc0, 0, 0, 0);
            acc1 = __builtin_amdgcn_mfma_f32_16x16x32_bf16(aq[1][h * 2 + 0], b0, acc1, 0, 0, 0);
            acc1 = __builtin_amdgcn_mfma_f32_16x16x32_bf16(aq[1][h * 2 + 1], b1, acc1, 0, 0, 0);
            #pragma unroll
            for (int r = 0; r < 4; r++) {
                scores32[(h * 32 + quad * 4 + r) * PFP + sub * 16 + l16] = acc0[r];
                scores32[(h * 32 + 16 + quad * 4 + r) * PFP + sub * 16 + l16] = acc1[r];
            }
        }
    }
    __syncthreads();                                             // b3

    // ---- masked softmax: 64 rows, 4 rows/wave; bf16 P written in-place.
    //      P written over full NCMAX width (exact 0 beyond valid window). ----
    {
        #pragma unroll
        for (int rr = 0; rr < 4; rr++) {
            int row = wid + rr * 16;            // 0..63
            int qq  = row & 31;
            int sg  = sh_s[qq];
            float vals[6]; int ok[6];
            float mx = -1e30f;
            #pragma unroll
            for (int i = 0; i < 6; i++) {
                int c = lane + 64 * i;
                float v = scores32[row * PFP + c] * 0.125f;
                int key = u0 + c;
                int o2 = (c < ncols) && (key >= sg) && (key < sg + 128);
                vals[i] = v; ok[i] = o2;
                if (o2) mx = fmaxf(mx, v);
            }
            #pragma unroll
            for (int off = 1; off < 64; off <<= 1) mx = fmaxf(mx, __shfl_xor(mx, off));
            float sum = 0.f, e6[6];
            #pragma unroll
            for (int i = 0; i < 6; i++) {
                float e = ok[i] ? __expf(vals[i] - mx) : 0.f;
                e6[i] = e; sum += e;
            }
            #pragma unroll
            for (int off = 1; off < 64; off <<= 1) sum += __shfl_xor(sum, off);
            float inv = 1.f / sum;
            u16* prow = (u16*)&scores32[row * PFP];   // in-place bf16 P (row-local)
            #pragma unroll
            for (int i = 0; i < 6; i++) {
                int c = lane + 64 * i;
                prow[c] = f2bf(e6[i] * inv);          // exact 0 where !ok
            }
        }
    }
    __syncthreads();                                             // b4

    // ---- wout prefetch (consumed after b5) ----
    const int n0 = wid * 16;
    s16x8 wout[4];
    #pragma unroll
    for (int kc = 0; kc < 4; kc++)
        wout[kc] = *(const s16x8*)&outT[wtile(n0 + l16, kc * 32 + quad * 8, 128)];

    // ---- P @ V (MFMA): 16 waves = (col-tile, row-half); V from regs ----
    {
        int hh = ct >> 2;
        const u16* prow = (const u16*)&scores32[(hh * 32 + rh * 16 + l16) * PFP];
        f32x4 acc = (f32x4){0.f, 0.f, 0.f, 0.f};
        #pragma unroll
        for (int kc = 0; kc < 6; kc++) {
            s16x8 a = *(const s16x8*)&prow[kc * 32 + quad * 8];
            acc = __builtin_amdgcn_mfma_f32_16x16x32_bf16(a, vf[kc], acc, 0, 0, 0);
        }
        for (int kc = 6; kc < nkc; kc++) {       // rare tail
            s16x8 a = *(const s16x8*)&prow[kc * 32 + quad * 8];
            int koff = min(u0 + kc * 32 + quad * 8, 1016);
            s16x8 bfr = *(const s16x8*)&vtbf[vidx(b, ct * 16 + l16, koff)];
            acc = __builtin_amdgcn_mfma_f32_16x16x32_bf16(a, bfr, acc, 0, 0, 0);
        }
        #pragma unroll
        for (int r = 0; r < 4; r++)
            o_lds[(rh * 16 + quad * 4 + r) * 136 + ct * 16 + l16] = f2bf(acc[r]);
    }
    __syncthreads();                                             // b5

    // ---- modu GEMM + band GEMM (band needs only gammas — hoisted here) ----
    f32x4 ab[2][2];
    {
        s16x8 wband[4];
        #pragma unroll
        for (int l = 0; l < 2; l++)
            #pragma unroll
            for (int kc = 0; kc < 2; kc++)
                wband[l * 2 + kc] = *(const s16x8*)&bandT[wtile(n0 + l16, l * 64 + kc * 32 + quad * 8, 128)];

        f32x4 am0 = (f32x4){0.f, 0.f, 0.f, 0.f};
        f32x4 am1 = (f32x4){0.f, 0.f, 0.f, 0.f};
        #pragma unroll
        for (int kc = 0; kc < 4; kc++) {
            s16x8 a0 = *(const s16x8*)&o_lds[l16 * 136 + kc * 32 + quad * 8];
            s16x8 a1 = *(const s16x8*)&o_lds[(16 + l16) * 136 + kc * 32 + quad * 8];
            am0 = __builtin_amdgcn_mfma_f32_16x16x32_bf16(a0, wout[kc], am0, 0, 0, 0);
            am1 = __builtin_amdgcn_mfma_f32_16x16x32_bf16(a1, wout[kc], am1, 0, 0, 0);
        }
        #pragma unroll
        for (int l = 0; l < 2; l++) {
            ab[l][0] = (f32x4){0.f, 0.f, 0.f, 0.f};
            ab[l][1] = (f32x4){0.f, 0.f, 0.f, 0.f};
            #pragma unroll
            for (int kc = 0; kc < 2; kc++) {
                s16x8 a0 = *(const s16x8*)&gam_lds[(l * 32 + l16) * 72 + kc * 32 + quad * 8];
                s16x8 a1 = *(const s16x8*)&gam_lds[(l * 32 + 16 + l16) * 72 + kc * 32 + quad * 8];
                ab[l][0] = __builtin_amdgcn_mfma_f32_16x16x32_bf16(a0, wband[l * 2 + kc], ab[l][0], 0, 0, 0);
                ab[l][1] = __builtin_amdgcn_mfma_f32_16x16x32_bf16(a1, wband[l * 2 + kc], ab[l][1], 0, 0, 0);
            }
        }
        int col = n0 + l16;
        float bias = out_b[col];
        #pragma unroll
        for (int r = 0; r < 4; r++) {
            modu_lds[(quad * 4 + r) * 264 + col] = f2bf(am0[r] + bias);
            modu_lds[(16 + quad * 4 + r) * 264 + col] = f2bf(am1[r] + bias);
        }
    }
    __syncthreads();                                             // b6

    float m0f[2][4];
    #pragma unroll
    for (int l = 0; l < 2; l++) {
        f32x4 amod0 = (f32x4){0.f, 0.f, 0.f, 0.f};
        f32x4 amod1 = (f32x4){0.f, 0.f, 0.f, 0.f};
        #pragma unroll
        for (int kc = 0; kc < 8; kc++) {
            s16x8 bfr = *(const s16x8*)&modT[wtile(n0 + l16, l * 256 + kc * 32 + quad * 8, 512)];
            s16x8 a0 = *(const s16x8*)&modu_lds[l16 * 264 + kc * 32 + quad * 8];
            s16x8 a1 = *(const s16x8*)&modu_lds[(16 + l16) * 264 + kc * 32 + quad * 8];
            amod0 = __builtin_amdgcn_mfma_f32_16x16x32_bf16(a0, bfr, amod0, 0, 0, 0);
            amod1 = __builtin_amdgcn_mfma_f32_16x16x32_bf16(a1, bfr, amod1, 0, 0, 0);
        }
        int col = n0 + l16;
        float bb = band_b[l * 256 + col];
        float mb = mod_b[l * 256 + col];
        #pragma unroll
        for (int r = 0; r < 4; r++) {
            float h0 = fmaxf(ab[l][0][r] + bb, 0.f);
            float v0 = fmaxf(h0 + amod0[r] + mb, 0.f);
            float h1 = fmaxf(ab[l][1][r] + bb, 0.f);
            float v1 = fmaxf(h1 + amod1[r] + mb, 0.f);
            if (l == 0) { m0f[0][r] = v0; m0f[1][r] = v1; }
            else {
                s01_lds[(quad * 4 + r) * 264 + col] = f2bf(m0f[0][r] + v0);
                s01_lds[(16 + quad * 4 + r) * 264 + col] = f2bf(m0f[1][r] + v1);
            }
        }
    }
    __syncthreads();                                             // b7

    {   // h_v1 = relu(s01 @ hv_W + hv_b) + scalar head
        f32x4 ah0 = (f32x4){0.f, 0.f, 0.f, 0.f};
        f32x4 ah1 = (f32x4){0.f, 0.f, 0.f, 0.f};
        #pragma unroll
        for (int kc = 0; kc < 8; kc++) {
            s16x8 bfr = *(const s16x8*)&hvT[wtile(n0 + l16, kc * 32 + quad * 8, 256)];
            s16x8 a0 = *(const s16x8*)&s01_lds[l16 * 264 + kc * 32 + quad * 8];
            s16x8 a1 = *(const s16x8*)&s01_lds[(16 + l16) * 264 + kc * 32 + quad * 8];
            ah0 = __builtin_amdgcn_mfma_f32_16x16x32_bf16(a0, bfr, ah0, 0, 0, 0);
            ah1 = __builtin_amdgcn_mfma_f32_16x16x32_bf16(a1, bfr, ah1, 0, 0, 0);
        }
        int col = n0 + l16;
        float w0 = outl_W[col], w1 = outl_W[256 + col], hb = hv_b[col];
        #pragma unroll
        for (int r = 0; r < 4; r++) {
            float pv0 = m0f[0][r] * w0 + fmaxf(ah0[r] + hb, 0.f) * w1;
            float pv1 = m0f[1][r] * w0 + fmaxf(ah1[r] + hb, 0.f) * w1;
            #pragma unroll
            for (int off = 1; off < 16; off <<= 1) {
                pv0 += __shfl_xor(pv0, off);
                pv1 += __shfl_xor(pv1, off);
            }
            if (l16 == 0) {
                fin[wid * 32 + quad * 4 + r] = pv0;
                fin[wid * 32 + 16 + quad * 4 + r] = pv1;
            }
        }
    }
    __syncthreads();                                             // b8
    if (t < 32) {
        float s2 = outl_b[0] + outl_b[1];
        #pragma unroll
        for (int w = 0; w < 16; w++) s2 += fin[w * 32 + t];
        out[(size_t)b * QN + sh_pq[t]] = s2;   // scatter by permutation
    }
}

// ---------------------------------------------------------------------------
extern "C" void kernel_launch(void* const* d_in, const int* in_sizes, int n_in,
                              void* d_out, int out_size, void* d_ws, size_t ws_size,
                              hipStream_t stream)
{
    const float* x       = (const float*)d_in[0];
    const float* tokens  = (const float*)d_in[1];
    const float* query_W = (const float*)d_in[2];
    const float* query_b = (const float*)d_in[3];
    const float* q_W     = (const float*)d_in[4];
    const float* kv_W    = (const float*)d_in[5];
    const float* out_W   = (const float*)d_in[6];
    const float* out_b   = (const float*)d_in[7];
    const float* band_W  = (const float*)d_in[8];
    const float* band_b  = (const float*)d_in[9];
    const float* mod_W   = (const float*)d_in[10];
    const float* mod_b   = (const float*)d_in[11];
    const float* hv_W    = (const float*)d_in[12];
    const float* hv_b    = (const float*)d_in[13];
    const float* outl_W  = (const float*)d_in[14];
    const float* outl_b  = (const float*)d_in[15];
    const int*   gD      = (const int*)d_in[16];
    const int*   gH      = (const int*)d_in[17];
    const int*   gW      = (const int*)d_in[18];
    const int*   gT      = (const int*)d_in[19];

    float* ws   = (float*)d_ws;
    u16* qall   = (u16*)ws;                         // 4096*128 bf16
    u16* wb = (u16*)(ws + 524288);
    u16* kbf   = wb;                                // 2*1024*128 bf16 (tiled)
    u16* vtbf  = wb + 262144;                       // 2*128*1024 bf16 (tiled)
    u16* outT  = wb + 524288;                       // 32768 (tiled)
    u16* bandT = wb + 557056;                       // 32768 (tiled)
    u16* modT  = wb + 589824;                       // 131072 (tiled)
    u16* hvT   = wb + 720896;                       // 65536 (tiled)
    int* perm  = (int*)(wb + 786432);               // 4096 ints
    int* ssort = perm + 4096;                       // 4096 ints
    float* out = (float*)d_out;

    prep_kernel<<<225, 1024, 0, stream>>>(tokens, kv_W, x, query_W, query_b, q_W,
                                          out_W, band_W, mod_W, hv_W,
                                          gD, gH, gW, gT,
                                          qall, kbf, vtbf, outT, bandT, modT, hvT,
                                          perm, ssort);
    fused_kernel<<<256, 1024, 0, stream>>>(x, kbf, vtbf, qall, perm, ssort,
        outT, out_b, bandT, band_b, modT, mod_b, hvT, hv_b,
        outl_W, outl_b, out);
}